// Round 1
// baseline (4648.148 us; speedup 1.0000x reference)
//
#include <hip/hip_runtime.h>
#include <hip/hip_bf16.h>
#include <math.h>

#define N_NODES 50000
#define N_EDGES 800000
#define IN_F    128
#define HID     128
#define CLS     32
#define NHEAD   4

// ---------- order-preserving float<->uint map for atomicMax on floats ----------
static __device__ __forceinline__ unsigned int fmap_order(float f) {
    unsigned int b = __float_as_uint(f);
    return (b & 0x80000000u) ? ~b : (b | 0x80000000u);
}
static __device__ __forceinline__ float funmap_order(unsigned int u) {
    return __uint_as_float((u & 0x80000000u) ? (u & 0x7fffffffu) : ~u);
}

// ---------- fused Q/K/V projection: out[n][o] = dot(x[n], W[o]) + b[o] ----------
// x: [n, 128] f32. W*: [A, 128]. One block = 16 nodes staged in LDS.
template<int A>
__global__ __launch_bounds__(256) void qkv_gemm(
    const float* __restrict__ x,
    const float* __restrict__ Wq, const float* __restrict__ bq,
    const float* __restrict__ Wk, const float* __restrict__ bk,
    const float* __restrict__ Wv, const float* __restrict__ bv,
    float* __restrict__ qo, float* __restrict__ ko, float* __restrict__ vo,
    int n)
{
    constexpr int NPB = 16;          // nodes per block
    constexpr int G   = 256 / A;     // thread groups over nodes
    constexpr int JN  = NPB / G;     // nodes per thread
    __shared__ float4 xs[NPB * 32];  // 16 x 128 floats

    const int t = threadIdx.x;
    const int node0 = blockIdx.x * NPB;

    for (int i = t; i < NPB * 32; i += 256) {
        int nn = node0 + i / 32;
        xs[i] = (nn < n) ? ((const float4*)x)[(size_t)nn * 32 + (i & 31)]
                         : make_float4(0.f, 0.f, 0.f, 0.f);
    }
    __syncthreads();

    const int o = t % A;
    const int g = t / A;
    const float* Ws[3] = {Wq, Wk, Wv};
    const float* bs[3] = {bq, bk, bv};
    float*       os[3] = {qo, ko, vo};

    for (int mat = 0; mat < 3; ++mat) {
        const float4* Wrow = (const float4*)(Ws[mat] + (size_t)o * IN_F);
        float accv[JN];
#pragma unroll
        for (int j = 0; j < JN; ++j) accv[j] = 0.f;
        for (int c = 0; c < 32; ++c) {
            float4 w = Wrow[c];
#pragma unroll
            for (int j = 0; j < JN; ++j) {
                float4 xv = xs[(g + j * G) * 32 + c];
                accv[j] += w.x * xv.x + w.y * xv.y + w.z * xv.z + w.w * xv.w;
            }
        }
        float bb = bs[mat][o];
#pragma unroll
        for (int j = 0; j < JN; ++j) {
            int nn = node0 + g + j * G;
            if (nn < n) os[mat][(size_t)nn * A + o] = accv[j] + bb;
        }
    }
}

// ---------- per-edge scores + segment max (over src) ----------
template<int DK>
__global__ __launch_bounds__(256) void edge_scores(
    const float* __restrict__ q, const float* __restrict__ k,
    const int* __restrict__ src, const int* __restrict__ dst,
    float* __restrict__ sc, unsigned int* __restrict__ mu,
    int nE, float scale)
{
    int idx = blockIdx.x * 256 + threadIdx.x;   // e*NHEAD + h
    if (idx >= nE * NHEAD) return;
    int e = idx >> 2, h = idx & 3;
    int s = src[e], d = dst[e];
    const float4* qp = (const float4*)(q + (size_t)s * (NHEAD * DK) + h * DK);
    const float4* kp = (const float4*)(k + (size_t)d * (NHEAD * DK) + h * DK);
    float acc = 0.f;
#pragma unroll
    for (int c = 0; c < DK / 4; ++c) {
        float4 a = qp[c], b = kp[c];
        acc += a.x * b.x + a.y * b.y + a.z * b.z + a.w * b.w;
    }
    acc *= scale;
    sc[idx] = acc;
    atomicMax(&mu[s * NHEAD + h], fmap_order(acc));
}

// ---------- exp(score - max) + segment denom sum ----------
__global__ __launch_bounds__(256) void edge_exp(
    float* __restrict__ sc, const unsigned int* __restrict__ mu,
    float* __restrict__ den, const int* __restrict__ src, int nE)
{
    int idx = blockIdx.x * 256 + threadIdx.x;
    if (idx >= nE * NHEAD) return;
    int e = idx >> 2, h = idx & 3;
    int s = src[e];
    float mval = funmap_order(mu[s * NHEAD + h]);
    float ex = expf(sc[idx] - mval);
    sc[idx] = ex;
    atomicAdd(&den[s * NHEAD + h], ex);
}

// ---------- scatter: acc[src] += beta * attn * v[dst] ----------
template<int DK>
__global__ __launch_bounds__(256) void edge_scatter(
    const float* __restrict__ sc, const float* __restrict__ den,
    const float* __restrict__ v,
    const int* __restrict__ src, const int* __restrict__ dst,
    float* __restrict__ acc, int nE, float beta)
{
    constexpr int CH = NHEAD * DK / 4;   // float4 chunks per edge
    int idx = blockIdx.x * 256 + threadIdx.x;
    if (idx >= nE * CH) return;
    int e = idx / CH;
    int r = idx % CH;
    int h = r / (DK / 4);
    int s = src[e], d = dst[e];
    float attn = sc[e * NHEAD + h] / (den[s * NHEAD + h] + 1e-16f);
    float w = beta * attn;
    float4 vv = ((const float4*)(v + (size_t)d * (NHEAD * DK)))[r];
    float* ap = acc + (size_t)s * (NHEAD * DK) + r * 4;
    atomicAdd(ap + 0, w * vv.x);
    atomicAdd(ap + 1, w * vv.y);
    atomicAdd(ap + 2, w * vv.z);
    atomicAdd(ap + 3, w * vv.w);
}

// ---------- elementwise ELU (in place) ----------
__global__ __launch_bounds__(256) void elu_inplace(float* __restrict__ a, int count)
{
    int i = blockIdx.x * 256 + threadIdx.x;
    if (i >= count) return;
    float x = a[i];
    a[i] = x > 0.f ? x : expm1f(x);
}

// ---------- row log_softmax over 32 classes ----------
__global__ __launch_bounds__(256) void logsoftmax32(
    const float* __restrict__ lg, float* __restrict__ out, int n)
{
    int t = threadIdx.x;
    int node = blockIdx.x * 8 + t / 32;
    int c = t % 32;
    if (node >= n) return;
    float x = lg[(size_t)node * 32 + c];
    float mx = x;
#pragma unroll
    for (int o = 16; o; o >>= 1) mx = fmaxf(mx, __shfl_xor(mx, o, 32));
    float ex = expf(x - mx);
    float sm = ex;
#pragma unroll
    for (int o = 16; o; o >>= 1) sm += __shfl_xor(sm, o, 32);
    out[(size_t)node * 32 + c] = x - mx - logf(sm);
}

extern "C" void kernel_launch(void* const* d_in, const int* in_sizes, int n_in,
                              void* d_out, int out_size, void* d_ws, size_t ws_size,
                              hipStream_t stream)
{
    const float* x   = (const float*)d_in[0];
    const float* Wq0 = (const float*)d_in[1];
    const float* bq0 = (const float*)d_in[2];
    const float* Wk0 = (const float*)d_in[3];
    const float* bk0 = (const float*)d_in[4];
    const float* Wv0 = (const float*)d_in[5];
    const float* bv0 = (const float*)d_in[6];
    const float* Wq1 = (const float*)d_in[7];
    const float* bq1 = (const float*)d_in[8];
    const float* Wk1 = (const float*)d_in[9];
    const float* bk1 = (const float*)d_in[10];
    const float* Wv1 = (const float*)d_in[11];
    const float* bv1 = (const float*)d_in[12];
    const int* edges[4] = {(const int*)d_in[13], (const int*)d_in[14],
                           (const int*)d_in[15], (const int*)d_in[16]};

    char* w = (char*)d_ws;
    float* q   = (float*)w; w += (size_t)N_NODES * HID * 4;
    float* kk  = (float*)w; w += (size_t)N_NODES * HID * 4;
    float* v   = (float*)w; w += (size_t)N_NODES * HID * 4;
    float* acc = (float*)w; w += (size_t)N_NODES * HID * 4;   // layer-0 out -> elu -> h
    float* lg  = (float*)w; w += (size_t)N_NODES * CLS * 4;   // layer-1 logits
    float* sc  = (float*)w; w += (size_t)N_EDGES * NHEAD * 4;
    unsigned int* mu = (unsigned int*)w; w += (size_t)N_NODES * NHEAD * 4;
    float* den = (float*)w; w += (size_t)N_NODES * NHEAD * 4;

    const int EH = N_EDGES * NHEAD;
    float* out = (float*)d_out;

    // ================= layer 0 (A=128, dk=32) =================
    hipMemsetAsync(acc, 0, (size_t)N_NODES * HID * 4, stream);
    for (int hop = 0; hop < 2; ++hop) {
        float beta = hop ? 0.5f : 1.0f;
        qkv_gemm<HID><<<(N_NODES + 15) / 16, 256, 0, stream>>>(
            x,
            Wq0 + (size_t)hop * HID * IN_F, bq0 + (size_t)hop * HID,
            Wk0 + (size_t)hop * HID * IN_F, bk0 + (size_t)hop * HID,
            Wv0 + (size_t)hop * HID * IN_F, bv0 + (size_t)hop * HID,
            q, kk, v, N_NODES);
        hipMemsetAsync(mu, 0, (size_t)N_NODES * NHEAD * 4, stream);
        hipMemsetAsync(den, 0, (size_t)N_NODES * NHEAD * 4, stream);
        const int* s = edges[hop];
        const int* d = edges[hop] + N_EDGES;
        edge_scores<32><<<(EH + 255) / 256, 256, 0, stream>>>(
            q, kk, s, d, sc, mu, N_EDGES, 1.f / sqrtf(32.f));
        edge_exp<<<(EH + 255) / 256, 256, 0, stream>>>(sc, mu, den, s, N_EDGES);
        edge_scatter<32><<<(N_EDGES * 32 + 255) / 256, 256, 0, stream>>>(
            sc, den, v, s, d, acc, N_EDGES, beta);
    }
    elu_inplace<<<(N_NODES * HID + 255) / 256, 256, 0, stream>>>(acc, N_NODES * HID);

    // ================= layer 1 (A=32, dk=8) =================
    hipMemsetAsync(lg, 0, (size_t)N_NODES * CLS * 4, stream);
    for (int hop = 0; hop < 2; ++hop) {
        float beta = hop ? 0.5f : 1.0f;
        qkv_gemm<CLS><<<(N_NODES + 15) / 16, 256, 0, stream>>>(
            acc,
            Wq1 + (size_t)hop * CLS * IN_F, bq1 + (size_t)hop * CLS,
            Wk1 + (size_t)hop * CLS * IN_F, bk1 + (size_t)hop * CLS,
            Wv1 + (size_t)hop * CLS * IN_F, bv1 + (size_t)hop * CLS,
            q, kk, v, N_NODES);
        hipMemsetAsync(mu, 0, (size_t)N_NODES * NHEAD * 4, stream);
        hipMemsetAsync(den, 0, (size_t)N_NODES * NHEAD * 4, stream);
        const int* s = edges[2 + hop];
        const int* d = edges[2 + hop] + N_EDGES;
        edge_scores<8><<<(EH + 255) / 256, 256, 0, stream>>>(
            q, kk, s, d, sc, mu, N_EDGES, 1.f / sqrtf(8.f));
        edge_exp<<<(EH + 255) / 256, 256, 0, stream>>>(sc, mu, den, s, N_EDGES);
        edge_scatter<8><<<(N_EDGES * 8 + 255) / 256, 256, 0, stream>>>(
            sc, den, v, s, d, lg, N_EDGES, beta);
    }
    logsoftmax32<<<(N_NODES + 7) / 8, 256, 0, stream>>>(lg, out, N_NODES);
}

// Round 2
// 1505.389 us; speedup vs baseline: 3.0877x; 3.0877x over previous
//
#include <hip/hip_runtime.h>
#include <hip/hip_bf16.h>
#include <math.h>

#define N_NODES 50000
#define N_EDGES 800000
#define IN_F    128
#define HID     128
#define CLS     32
#define NHEAD   4

// ================= CSR build =================
__global__ __launch_bounds__(256) void hist_kernel(
    const int* __restrict__ src, int* __restrict__ deg, int nE)
{
    int e = blockIdx.x * 256 + threadIdx.x;
    if (e < nE) atomicAdd(&deg[src[e]], 1);
}

// one block per edge-set; exclusive scan of deg -> rowptr (+cursor copy)
__global__ __launch_bounds__(1024) void scan4(
    const int* __restrict__ deg, int* __restrict__ rowptr,
    int* __restrict__ cursor, int n)
{
    const int s = blockIdx.x;
    const int* d = deg + (size_t)s * n;
    int* rp = rowptr + (size_t)s * n;
    int* cu = cursor + (size_t)s * n;
    __shared__ int tmp[1024];
    __shared__ int carry;
    if (threadIdx.x == 0) carry = 0;
    __syncthreads();
    for (int base = 0; base < n; base += 1024) {
        int i = base + threadIdx.x;
        int val = (i < n) ? d[i] : 0;
        tmp[threadIdx.x] = val;
        __syncthreads();
        for (int o = 1; o < 1024; o <<= 1) {
            int t = (threadIdx.x >= o) ? tmp[threadIdx.x - o] : 0;
            __syncthreads();
            tmp[threadIdx.x] += t;
            __syncthreads();
        }
        int excl = tmp[threadIdx.x] - val;
        if (i < n) { rp[i] = carry + excl; cu[i] = carry + excl; }
        __syncthreads();
        if (threadIdx.x == 1023) carry += tmp[1023];
        __syncthreads();
    }
}

__global__ __launch_bounds__(256) void fill_kernel(
    const int* __restrict__ src, const int* __restrict__ dst,
    int* __restrict__ cursor, int* __restrict__ col, int nE)
{
    int e = blockIdx.x * 256 + threadIdx.x;
    if (e < nE) {
        int p = atomicAdd(&cursor[src[e]], 1);
        col[p] = dst[e];
    }
}

// ================= fused Q/K/V projection =================
template<int A>
__global__ __launch_bounds__(256) void qkv_gemm(
    const float* __restrict__ x,
    const float* __restrict__ Wq, const float* __restrict__ bq,
    const float* __restrict__ Wk, const float* __restrict__ bk,
    const float* __restrict__ Wv, const float* __restrict__ bv,
    float* __restrict__ qo, float* __restrict__ ko, float* __restrict__ vo,
    int n)
{
    constexpr int NPB = 16;
    constexpr int G   = 256 / A;
    constexpr int JN  = NPB / G;
    __shared__ float4 xs[NPB * 32];

    const int t = threadIdx.x;
    const int node0 = blockIdx.x * NPB;

    for (int i = t; i < NPB * 32; i += 256) {
        int nn = node0 + i / 32;
        xs[i] = (nn < n) ? ((const float4*)x)[(size_t)nn * 32 + (i & 31)]
                         : make_float4(0.f, 0.f, 0.f, 0.f);
    }
    __syncthreads();

    const int o = t % A;
    const int g = t / A;
    const float* Ws[3] = {Wq, Wk, Wv};
    const float* bs[3] = {bq, bk, bv};
    float*       os[3] = {qo, ko, vo};

    for (int mat = 0; mat < 3; ++mat) {
        const float4* Wrow = (const float4*)(Ws[mat] + (size_t)o * IN_F);
        float accv[JN];
#pragma unroll
        for (int j = 0; j < JN; ++j) accv[j] = 0.f;
        for (int c = 0; c < 32; ++c) {
            float4 w = Wrow[c];
#pragma unroll
            for (int j = 0; j < JN; ++j) {
                float4 xv = xs[(g + j * G) * 32 + c];
                accv[j] += w.x * xv.x + w.y * xv.y + w.z * xv.z + w.w * xv.w;
            }
        }
        float bb = bs[mat][o];
#pragma unroll
        for (int j = 0; j < JN; ++j) {
            int nn = node0 + g + j * G;
            if (nn < n) os[mat][(size_t)nn * A + o] = accv[j] + bb;
        }
    }
}

// ================= fused per-node online-softmax gather (A=128, dk=32) ==========
// One wave per src node. Lane holds float2 (elements 2*lane, 2*lane+1) of q-row
// and of the output accumulator; both elements belong to head lane/16.
__global__ __launch_bounds__(256) void gat_node128(
    const float* __restrict__ q, const float* __restrict__ k,
    const float* __restrict__ v,
    const int* __restrict__ rowptr, const int* __restrict__ deg,
    const int* __restrict__ col,
    float* __restrict__ out, float beta, float scale, int n)
{
    int wid  = (blockIdx.x * 256 + threadIdx.x) >> 6;
    int lane = threadIdx.x & 63;
    if (wid >= n) return;
    int start = rowptr[wid], cnt = deg[wid];
    float2 qv = ((const float2*)q)[(size_t)wid * 64 + lane];
    float m = -INFINITY, l = 0.f, ax = 0.f, ay = 0.f;
    for (int t = 0; t < cnt; ++t) {
        int d = col[start + t];
        float2 kv = ((const float2*)k)[(size_t)d * 64 + lane];
        float2 vv = ((const float2*)v)[(size_t)d * 64 + lane];
        float p = qv.x * kv.x + qv.y * kv.y;
        p += __shfl_xor(p, 1);
        p += __shfl_xor(p, 2);
        p += __shfl_xor(p, 4);
        p += __shfl_xor(p, 8);          // sum over 16-lane head group
        float s = p * scale;
        float M = fmaxf(m, s);
        float c = __expf(m - M);        // m=-inf on first edge -> c=0
        float e = __expf(s - M);
        l  = l * c + e;
        ax = ax * c + e * vv.x;
        ay = ay * c + e * vv.y;
        m  = M;
    }
    float inv = (l > 0.f) ? 1.f / l : 0.f;
    float2* op = (float2*)out + (size_t)wid * 64 + lane;
    float2 cur = *op;
    cur.x += beta * ax * inv;
    cur.y += beta * ay * inv;
    *op = cur;
}

// ================= fused per-node gather (A=32, dk=8) =================
// One wave per node; 4 edges in flight (16 lanes each). Lane (g,il): elements
// 2*il, 2*il+1 (head il/4) of edge start + t, t ≡ g (mod 4). Merge at end.
__global__ __launch_bounds__(256) void gat_node32(
    const float* __restrict__ q, const float* __restrict__ k,
    const float* __restrict__ v,
    const int* __restrict__ rowptr, const int* __restrict__ deg,
    const int* __restrict__ col,
    float* __restrict__ out, float beta, float scale, int n)
{
    int wid  = (blockIdx.x * 256 + threadIdx.x) >> 6;
    int lane = threadIdx.x & 63;
    if (wid >= n) return;
    int start = rowptr[wid], cnt = deg[wid];
    int g  = lane >> 4;
    int il = lane & 15;
    float2 qv = ((const float2*)q)[(size_t)wid * 16 + il];
    float m = -INFINITY, l = 0.f, ax = 0.f, ay = 0.f;
    for (int t = g; t < cnt; t += 4) {
        int d = col[start + t];
        float2 kv = ((const float2*)k)[(size_t)d * 16 + il];
        float2 vv = ((const float2*)v)[(size_t)d * 16 + il];
        float p = qv.x * kv.x + qv.y * kv.y;
        p += __shfl_xor(p, 1);
        p += __shfl_xor(p, 2);          // sum over 4-lane head group
        float s = p * scale;
        float M = fmaxf(m, s);
        float c = __expf(m - M);
        float e = __expf(s - M);
        l  = l * c + e;
        ax = ax * c + e * vv.x;
        ay = ay * c + e * vv.y;
        m  = M;
    }
    // merge the 4 edge-groups (offsets 16, 32)
#pragma unroll
    for (int off = 16; off <= 32; off <<= 1) {
        float mo  = __shfl_xor(m, off);
        float lo  = __shfl_xor(l, off);
        float axo = __shfl_xor(ax, off);
        float ayo = __shfl_xor(ay, off);
        float M  = fmaxf(m, mo);
        float cA = (l  > 0.f) ? __expf(m  - M) : 0.f;
        float cB = (lo > 0.f) ? __expf(mo - M) : 0.f;
        l  = l * cA + lo * cB;
        ax = ax * cA + axo * cB;
        ay = ay * cA + ayo * cB;
        m  = M;
    }
    if (g == 0) {
        float inv = (l > 0.f) ? 1.f / l : 0.f;
        float2* op = (float2*)out + (size_t)wid * 16 + il;
        float2 cur = *op;
        cur.x += beta * ax * inv;
        cur.y += beta * ay * inv;
        *op = cur;
    }
}

// ================= elementwise ELU (in place) =================
__global__ __launch_bounds__(256) void elu_inplace(float* __restrict__ a, int count)
{
    int i = blockIdx.x * 256 + threadIdx.x;
    if (i >= count) return;
    float x = a[i];
    a[i] = x > 0.f ? x : expm1f(x);
}

// ================= row log_softmax over 32 classes =================
__global__ __launch_bounds__(256) void logsoftmax32(
    const float* __restrict__ lg, float* __restrict__ out, int n)
{
    int t = threadIdx.x;
    int node = blockIdx.x * 8 + t / 32;
    int c = t % 32;
    if (node >= n) return;
    float x = lg[(size_t)node * 32 + c];
    float mx = x;
#pragma unroll
    for (int o = 16; o; o >>= 1) mx = fmaxf(mx, __shfl_xor(mx, o, 32));
    float ex = expf(x - mx);
    float sm = ex;
#pragma unroll
    for (int o = 16; o; o >>= 1) sm += __shfl_xor(sm, o, 32);
    out[(size_t)node * 32 + c] = x - mx - logf(sm);
}

extern "C" void kernel_launch(void* const* d_in, const int* in_sizes, int n_in,
                              void* d_out, int out_size, void* d_ws, size_t ws_size,
                              hipStream_t stream)
{
    const float* x   = (const float*)d_in[0];
    const float* Wq0 = (const float*)d_in[1];
    const float* bq0 = (const float*)d_in[2];
    const float* Wk0 = (const float*)d_in[3];
    const float* bk0 = (const float*)d_in[4];
    const float* Wv0 = (const float*)d_in[5];
    const float* bv0 = (const float*)d_in[6];
    const float* Wq1 = (const float*)d_in[7];
    const float* bq1 = (const float*)d_in[8];
    const float* Wk1 = (const float*)d_in[9];
    const float* bk1 = (const float*)d_in[10];
    const float* Wv1 = (const float*)d_in[11];
    const float* bv1 = (const float*)d_in[12];
    const int* esrc[4] = {(const int*)d_in[13], (const int*)d_in[14],
                          (const int*)d_in[15], (const int*)d_in[16]};

    char* w = (char*)d_ws;
    float* q   = (float*)w; w += (size_t)N_NODES * HID * 4;
    float* kk  = (float*)w; w += (size_t)N_NODES * HID * 4;
    float* v   = (float*)w; w += (size_t)N_NODES * HID * 4;
    float* acc = (float*)w; w += (size_t)N_NODES * HID * 4;   // layer-0 out -> elu -> h
    float* lg  = (float*)w; w += (size_t)N_NODES * CLS * 4;   // layer-1 logits
    int* deg    = (int*)w; w += (size_t)4 * N_NODES * 4;
    int* rowptr = (int*)w; w += (size_t)4 * N_NODES * 4;
    int* cursor = (int*)w; w += (size_t)4 * N_NODES * 4;
    int* col    = (int*)w; w += (size_t)4 * N_EDGES * 4;

    float* out = (float*)d_out;
    const int EB = (N_EDGES + 255) / 256;
    const int NB = (N_NODES + 3) / 4;       // 4 waves (nodes) per 256-block

    // ---------- build 4 CSRs ----------
    hipMemsetAsync(deg, 0, (size_t)4 * N_NODES * 4, stream);
    for (int s = 0; s < 4; ++s)
        hist_kernel<<<EB, 256, 0, stream>>>(esrc[s], deg + (size_t)s * N_NODES, N_EDGES);
    scan4<<<4, 1024, 0, stream>>>(deg, rowptr, cursor, N_NODES);
    for (int s = 0; s < 4; ++s)
        fill_kernel<<<EB, 256, 0, stream>>>(esrc[s], esrc[s] + N_EDGES,
                                            cursor + (size_t)s * N_NODES,
                                            col + (size_t)s * N_EDGES, N_EDGES);

    // ================= layer 0 (A=128, dk=32) =================
    hipMemsetAsync(acc, 0, (size_t)N_NODES * HID * 4, stream);
    for (int hop = 0; hop < 2; ++hop) {
        float beta = hop ? 0.5f : 1.0f;
        qkv_gemm<HID><<<(N_NODES + 15) / 16, 256, 0, stream>>>(
            x,
            Wq0 + (size_t)hop * HID * IN_F, bq0 + (size_t)hop * HID,
            Wk0 + (size_t)hop * HID * IN_F, bk0 + (size_t)hop * HID,
            Wv0 + (size_t)hop * HID * IN_F, bv0 + (size_t)hop * HID,
            q, kk, v, N_NODES);
        gat_node128<<<NB, 256, 0, stream>>>(
            q, kk, v,
            rowptr + (size_t)hop * N_NODES, deg + (size_t)hop * N_NODES,
            col + (size_t)hop * N_EDGES,
            acc, beta, 1.f / sqrtf(32.f), N_NODES);
    }
    elu_inplace<<<(N_NODES * HID + 255) / 256, 256, 0, stream>>>(acc, N_NODES * HID);

    // ================= layer 1 (A=32, dk=8) =================
    hipMemsetAsync(lg, 0, (size_t)N_NODES * CLS * 4, stream);
    for (int hop = 0; hop < 2; ++hop) {
        float beta = hop ? 0.5f : 1.0f;
        qkv_gemm<CLS><<<(N_NODES + 15) / 16, 256, 0, stream>>>(
            acc,
            Wq1 + (size_t)hop * CLS * IN_F, bq1 + (size_t)hop * CLS,
            Wk1 + (size_t)hop * CLS * IN_F, bk1 + (size_t)hop * CLS,
            Wv1 + (size_t)hop * CLS * IN_F, bv1 + (size_t)hop * CLS,
            q, kk, v, N_NODES);
        gat_node32<<<NB, 256, 0, stream>>>(
            q, kk, v,
            rowptr + (size_t)(2 + hop) * N_NODES, deg + (size_t)(2 + hop) * N_NODES,
            col + (size_t)(2 + hop) * N_EDGES,
            lg, beta, 1.f / sqrtf(8.f), N_NODES);
    }
    logsoftmax32<<<(N_NODES + 7) / 8, 256, 0, stream>>>(lg, out, N_NODES);
}

// Round 3
// 963.971 us; speedup vs baseline: 4.8219x; 1.5617x over previous
//
#include <hip/hip_runtime.h>
#include <hip/hip_bf16.h>
#include <math.h>

#define N_NODES 50000
#define N_EDGES 800000
#define IN_F    128
#define HID     128
#define CLS     32
#define NHEAD   4

typedef __attribute__((ext_vector_type(8))) short  short8;
typedef __attribute__((ext_vector_type(4))) float  floatx4;

// ---------- f32 -> bf16 (RNE) ----------
static __device__ __forceinline__ unsigned short f2bf(float f) {
    unsigned int u = __float_as_uint(f);
    return (unsigned short)((u + 0x7fffu + ((u >> 16) & 1u)) >> 16);
}

__global__ __launch_bounds__(256) void f32_to_bf16(
    const float* __restrict__ in, unsigned short* __restrict__ out, int count)
{
    int i = blockIdx.x * 256 + threadIdx.x;
    if (i < count) out[i] = f2bf(in[i]);
}

// ================= CSR build =================
__global__ __launch_bounds__(256) void hist_kernel(
    const int* __restrict__ src, int* __restrict__ deg, int nE)
{
    int e = blockIdx.x * 256 + threadIdx.x;
    if (e < nE) atomicAdd(&deg[src[e]], 1);
}

__global__ __launch_bounds__(1024) void scan4(
    const int* __restrict__ deg, int* __restrict__ rowptr,
    int* __restrict__ cursor, int n)
{
    const int s = blockIdx.x;
    const int* d = deg + (size_t)s * n;
    int* rp = rowptr + (size_t)s * n;
    int* cu = cursor + (size_t)s * n;
    __shared__ int tmp[1024];
    __shared__ int carry;
    if (threadIdx.x == 0) carry = 0;
    __syncthreads();
    for (int base = 0; base < n; base += 1024) {
        int i = base + threadIdx.x;
        int val = (i < n) ? d[i] : 0;
        tmp[threadIdx.x] = val;
        __syncthreads();
        for (int o = 1; o < 1024; o <<= 1) {
            int t = (threadIdx.x >= o) ? tmp[threadIdx.x - o] : 0;
            __syncthreads();
            tmp[threadIdx.x] += t;
            __syncthreads();
        }
        int excl = tmp[threadIdx.x] - val;
        if (i < n) { rp[i] = carry + excl; cu[i] = carry + excl; }
        __syncthreads();
        if (threadIdx.x == 1023) carry += tmp[1023];
        __syncthreads();
    }
}

__global__ __launch_bounds__(256) void fill_kernel(
    const int* __restrict__ src, const int* __restrict__ dst,
    int* __restrict__ cursor, int* __restrict__ col, int nE)
{
    int e = blockIdx.x * 256 + threadIdx.x;
    if (e < nE) {
        int p = atomicAdd(&cursor[src[e]], 1);
        col[p] = dst[e];
    }
}

// ================= MFMA Q/K/V projection =================
// One wave = 16 nodes. A-frag: x[node0 + lane%16][k], k = ks*32 + (lane/16)*8 + j.
// B-frag: W[nt*16 + lane%16][same k]  (B[k][n] = W[n][k]).
// D: col = lane&15 (output), row = (lane>>4)*4 + reg (node). [m89-verified layout]
static __device__ __forceinline__ short8 pack8(const float* p) {
    float4 a = *(const float4*)p;
    float4 b = *(const float4*)(p + 4);
    short8 v;
    v[0] = (short)f2bf(a.x); v[1] = (short)f2bf(a.y);
    v[2] = (short)f2bf(a.z); v[3] = (short)f2bf(a.w);
    v[4] = (short)f2bf(b.x); v[5] = (short)f2bf(b.y);
    v[6] = (short)f2bf(b.z); v[7] = (short)f2bf(b.w);
    return v;
}

template<int NT, int A>
__device__ __forceinline__ void mat_mfma(
    const short8* xf, const unsigned short* W, const float* b,
    float* o, int node0, int r, int kg)
{
    floatx4 acc[NT];
#pragma unroll
    for (int nt = 0; nt < NT; ++nt) {
        float bb = b[nt * 16 + r];
        acc[nt] = (floatx4){bb, bb, bb, bb};
    }
#pragma unroll
    for (int ks = 0; ks < 4; ++ks) {
#pragma unroll
        for (int nt = 0; nt < NT; ++nt) {
            short8 wf = *(const short8*)((const short*)W + (size_t)(nt * 16 + r) * IN_F + ks * 32 + kg * 8);
            acc[nt] = __builtin_amdgcn_mfma_f32_16x16x32_bf16(xf[ks], wf, acc[nt], 0, 0, 0);
        }
    }
#pragma unroll
    for (int nt = 0; nt < NT; ++nt)
#pragma unroll
        for (int reg = 0; reg < 4; ++reg)
            o[(size_t)(node0 + kg * 4 + reg) * A + nt * 16 + r] = acc[nt][reg];
}

template<int A>
__global__ __launch_bounds__(256) void qkv_mfma(
    const float* __restrict__ x,
    const unsigned short* __restrict__ Wqb, const float* __restrict__ bq,
    const unsigned short* __restrict__ Wkb, const float* __restrict__ bk,
    const unsigned short* __restrict__ Wvb, const float* __restrict__ bv,
    float* __restrict__ qo, float* __restrict__ ko, float* __restrict__ vo,
    int n)
{
    constexpr int NT = A / 16;
    const int wave = threadIdx.x >> 6;
    const int lane = threadIdx.x & 63;
    const int node0 = blockIdx.x * 64 + wave * 16;
    if (node0 >= n) return;
    const int r  = lane & 15;
    const int kg = lane >> 4;

    short8 xf[4];
    const float* xr = x + (size_t)(node0 + r) * IN_F + kg * 8;
#pragma unroll
    for (int ks = 0; ks < 4; ++ks) xf[ks] = pack8(xr + ks * 32);

    mat_mfma<NT, A>(xf, Wqb, bq, qo, node0, r, kg);
    mat_mfma<NT, A>(xf, Wkb, bk, ko, node0, r, kg);
    mat_mfma<NT, A>(xf, Wvb, bv, vo, node0, r, kg);
}

// ================= fused per-node online-softmax gather (A=128, dk=32) ==========
__global__ __launch_bounds__(256) void gat_node128(
    const float* __restrict__ q, const float* __restrict__ k,
    const float* __restrict__ v,
    const int* __restrict__ rowptr, const int* __restrict__ deg,
    const int* __restrict__ col,
    float* __restrict__ out, float beta, float scale, int n)
{
    int wid  = (blockIdx.x * 256 + threadIdx.x) >> 6;
    int lane = threadIdx.x & 63;
    if (wid >= n) return;
    int start = rowptr[wid], cnt = deg[wid];
    float2 qv = ((const float2*)q)[(size_t)wid * 64 + lane];
    float m = -INFINITY, l = 0.f, ax = 0.f, ay = 0.f;
    for (int t = 0; t < cnt; ++t) {
        int d = col[start + t];
        float2 kv = ((const float2*)k)[(size_t)d * 64 + lane];
        float2 vv = ((const float2*)v)[(size_t)d * 64 + lane];
        float p = qv.x * kv.x + qv.y * kv.y;
        p += __shfl_xor(p, 1);
        p += __shfl_xor(p, 2);
        p += __shfl_xor(p, 4);
        p += __shfl_xor(p, 8);
        float s = p * scale;
        float M = fmaxf(m, s);
        float c = __expf(m - M);
        float e = __expf(s - M);
        l  = l * c + e;
        ax = ax * c + e * vv.x;
        ay = ay * c + e * vv.y;
        m  = M;
    }
    float inv = (l > 0.f) ? 1.f / l : 0.f;
    float2* op = (float2*)out + (size_t)wid * 64 + lane;
    float2 cur = *op;
    cur.x += beta * ax * inv;
    cur.y += beta * ay * inv;
    *op = cur;
}

// ================= fused per-node gather (A=32, dk=8) =================
__global__ __launch_bounds__(256) void gat_node32(
    const float* __restrict__ q, const float* __restrict__ k,
    const float* __restrict__ v,
    const int* __restrict__ rowptr, const int* __restrict__ deg,
    const int* __restrict__ col,
    float* __restrict__ out, float beta, float scale, int n)
{
    int wid  = (blockIdx.x * 256 + threadIdx.x) >> 6;
    int lane = threadIdx.x & 63;
    if (wid >= n) return;
    int start = rowptr[wid], cnt = deg[wid];
    int g  = lane >> 4;
    int il = lane & 15;
    float2 qv = ((const float2*)q)[(size_t)wid * 16 + il];
    float m = -INFINITY, l = 0.f, ax = 0.f, ay = 0.f;
    for (int t = g; t < cnt; t += 4) {
        int d = col[start + t];
        float2 kv = ((const float2*)k)[(size_t)d * 16 + il];
        float2 vv = ((const float2*)v)[(size_t)d * 16 + il];
        float p = qv.x * kv.x + qv.y * kv.y;
        p += __shfl_xor(p, 1);
        p += __shfl_xor(p, 2);
        float s = p * scale;
        float M = fmaxf(m, s);
        float c = __expf(m - M);
        float e = __expf(s - M);
        l  = l * c + e;
        ax = ax * c + e * vv.x;
        ay = ay * c + e * vv.y;
        m  = M;
    }
#pragma unroll
    for (int off = 16; off <= 32; off <<= 1) {
        float mo  = __shfl_xor(m, off);
        float lo  = __shfl_xor(l, off);
        float axo = __shfl_xor(ax, off);
        float ayo = __shfl_xor(ay, off);
        float M  = fmaxf(m, mo);
        float cA = (l  > 0.f) ? __expf(m  - M) : 0.f;
        float cB = (lo > 0.f) ? __expf(mo - M) : 0.f;
        l  = l * cA + lo * cB;
        ax = ax * cA + axo * cB;
        ay = ay * cA + ayo * cB;
        m  = M;
    }
    if (g == 0) {
        float inv = (l > 0.f) ? 1.f / l : 0.f;
        float2* op = (float2*)out + (size_t)wid * 16 + il;
        float2 cur = *op;
        cur.x += beta * ax * inv;
        cur.y += beta * ay * inv;
        *op = cur;
    }
}

// ================= elementwise ELU (in place) =================
__global__ __launch_bounds__(256) void elu_inplace(float* __restrict__ a, int count)
{
    int i = blockIdx.x * 256 + threadIdx.x;
    if (i >= count) return;
    float x = a[i];
    a[i] = x > 0.f ? x : expm1f(x);
}

// ================= row log_softmax over 32 classes =================
__global__ __launch_bounds__(256) void logsoftmax32(
    const float* __restrict__ lg, float* __restrict__ out, int n)
{
    int t = threadIdx.x;
    int node = blockIdx.x * 8 + t / 32;
    int c = t % 32;
    if (node >= n) return;
    float x = lg[(size_t)node * 32 + c];
    float mx = x;
#pragma unroll
    for (int o = 16; o; o >>= 1) mx = fmaxf(mx, __shfl_xor(mx, o, 32));
    float ex = expf(x - mx);
    float sm = ex;
#pragma unroll
    for (int o = 16; o; o >>= 1) sm += __shfl_xor(sm, o, 32);
    out[(size_t)node * 32 + c] = x - mx - logf(sm);
}

extern "C" void kernel_launch(void* const* d_in, const int* in_sizes, int n_in,
                              void* d_out, int out_size, void* d_ws, size_t ws_size,
                              hipStream_t stream)
{
    const float* x   = (const float*)d_in[0];
    const float* Wq0 = (const float*)d_in[1];
    const float* bq0 = (const float*)d_in[2];
    const float* Wk0 = (const float*)d_in[3];
    const float* bk0 = (const float*)d_in[4];
    const float* Wv0 = (const float*)d_in[5];
    const float* bv0 = (const float*)d_in[6];
    const float* Wq1 = (const float*)d_in[7];
    const float* bq1 = (const float*)d_in[8];
    const float* Wk1 = (const float*)d_in[9];
    const float* bk1 = (const float*)d_in[10];
    const float* Wv1 = (const float*)d_in[11];
    const float* bv1 = (const float*)d_in[12];
    const int* esrc[4] = {(const int*)d_in[13], (const int*)d_in[14],
                          (const int*)d_in[15], (const int*)d_in[16]};

    char* w = (char*)d_ws;
    float* q   = (float*)w; w += (size_t)N_NODES * HID * 4;
    float* kk  = (float*)w; w += (size_t)N_NODES * HID * 4;
    float* v   = (float*)w; w += (size_t)N_NODES * HID * 4;
    float* acc = (float*)w; w += (size_t)N_NODES * HID * 4;   // layer-0 out -> elu -> h
    float* lg  = (float*)w; w += (size_t)N_NODES * CLS * 4;   // layer-1 logits
    int* deg    = (int*)w; w += (size_t)4 * N_NODES * 4;
    int* rowptr = (int*)w; w += (size_t)4 * N_NODES * 4;
    int* cursor = (int*)w; w += (size_t)4 * N_NODES * 4;
    int* col    = (int*)w; w += (size_t)4 * N_EDGES * 4;
    // bf16 weight buffers
    unsigned short* wq0b = (unsigned short*)w; w += (size_t)2 * HID * IN_F * 2;
    unsigned short* wk0b = (unsigned short*)w; w += (size_t)2 * HID * IN_F * 2;
    unsigned short* wv0b = (unsigned short*)w; w += (size_t)2 * HID * IN_F * 2;
    unsigned short* wq1b = (unsigned short*)w; w += (size_t)2 * CLS * IN_F * 2;
    unsigned short* wk1b = (unsigned short*)w; w += (size_t)2 * CLS * IN_F * 2;
    unsigned short* wv1b = (unsigned short*)w; w += (size_t)2 * CLS * IN_F * 2;

    float* out = (float*)d_out;
    const int EB = (N_EDGES + 255) / 256;
    const int NB = (N_NODES + 3) / 4;          // gat: 4 waves (nodes) / block
    const int QB = (N_NODES / 16 + 3) / 4;     // qkv: 4 waves (16 nodes ea) / block

    // ---------- convert weights to bf16 ----------
    const int W0 = 2 * HID * IN_F, W1 = 2 * CLS * IN_F;
    f32_to_bf16<<<(W0 + 255) / 256, 256, 0, stream>>>(Wq0, wq0b, W0);
    f32_to_bf16<<<(W0 + 255) / 256, 256, 0, stream>>>(Wk0, wk0b, W0);
    f32_to_bf16<<<(W0 + 255) / 256, 256, 0, stream>>>(Wv0, wv0b, W0);
    f32_to_bf16<<<(W1 + 255) / 256, 256, 0, stream>>>(Wq1, wq1b, W1);
    f32_to_bf16<<<(W1 + 255) / 256, 256, 0, stream>>>(Wk1, wk1b, W1);
    f32_to_bf16<<<(W1 + 255) / 256, 256, 0, stream>>>(Wv1, wv1b, W1);

    // ---------- build 4 CSRs ----------
    hipMemsetAsync(deg, 0, (size_t)4 * N_NODES * 4, stream);
    for (int s = 0; s < 4; ++s)
        hist_kernel<<<EB, 256, 0, stream>>>(esrc[s], deg + (size_t)s * N_NODES, N_EDGES);
    scan4<<<4, 1024, 0, stream>>>(deg, rowptr, cursor, N_NODES);
    for (int s = 0; s < 4; ++s)
        fill_kernel<<<EB, 256, 0, stream>>>(esrc[s], esrc[s] + N_EDGES,
                                            cursor + (size_t)s * N_NODES,
                                            col + (size_t)s * N_EDGES, N_EDGES);

    // ================= layer 0 (A=128, dk=32) =================
    hipMemsetAsync(acc, 0, (size_t)N_NODES * HID * 4, stream);
    for (int hop = 0; hop < 2; ++hop) {
        float beta = hop ? 0.5f : 1.0f;
        qkv_mfma<HID><<<QB, 256, 0, stream>>>(
            x,
            wq0b + (size_t)hop * HID * IN_F, bq0 + (size_t)hop * HID,
            wk0b + (size_t)hop * HID * IN_F, bk0 + (size_t)hop * HID,
            wv0b + (size_t)hop * HID * IN_F, bv0 + (size_t)hop * HID,
            q, kk, v, N_NODES);
        gat_node128<<<NB, 256, 0, stream>>>(
            q, kk, v,
            rowptr + (size_t)hop * N_NODES, deg + (size_t)hop * N_NODES,
            col + (size_t)hop * N_EDGES,
            acc, beta, 1.f / sqrtf(32.f), N_NODES);
    }
    elu_inplace<<<(N_NODES * HID + 255) / 256, 256, 0, stream>>>(acc, N_NODES * HID);

    // ================= layer 1 (A=32, dk=8) =================
    hipMemsetAsync(lg, 0, (size_t)N_NODES * CLS * 4, stream);
    for (int hop = 0; hop < 2; ++hop) {
        float beta = hop ? 0.5f : 1.0f;
        qkv_mfma<CLS><<<QB, 256, 0, stream>>>(
            acc,
            wq1b + (size_t)hop * CLS * IN_F, bq1 + (size_t)hop * CLS,
            wk1b + (size_t)hop * CLS * IN_F, bk1 + (size_t)hop * CLS,
            wv1b + (size_t)hop * CLS * IN_F, bv1 + (size_t)hop * CLS,
            q, kk, v, N_NODES);
        gat_node32<<<NB, 256, 0, stream>>>(
            q, kk, v,
            rowptr + (size_t)(2 + hop) * N_NODES, deg + (size_t)(2 + hop) * N_NODES,
            col + (size_t)(2 + hop) * N_EDGES,
            lg, beta, 1.f / sqrtf(8.f), N_NODES);
    }
    logsoftmax32<<<(N_NODES + 7) / 8, 256, 0, stream>>>(lg, out, N_NODES);
}

// Round 4
// 754.935 us; speedup vs baseline: 6.1570x; 1.2769x over previous
//
#include <hip/hip_runtime.h>
#include <hip/hip_bf16.h>
#include <math.h>

#define N_NODES 50000
#define N_EDGES 800000
#define IN_F    128
#define HID     128
#define CLS     32
#define NHEAD   4

typedef __attribute__((ext_vector_type(8))) short  short8;
typedef __attribute__((ext_vector_type(4))) float  floatx4;

// ---------- f32 -> bf16 (RNE) ----------
static __device__ __forceinline__ unsigned short f2bf(float f) {
    unsigned int u = __float_as_uint(f);
    return (unsigned short)((u + 0x7fffu + ((u >> 16) & 1u)) >> 16);
}
// packed uint (2x bf16) -> 2 floats; low ushort = even element
static __device__ __forceinline__ float2 bf2f2(unsigned int u) {
    return make_float2(__uint_as_float(u << 16), __uint_as_float(u & 0xffff0000u));
}

// ---------- weight conversion: 3 matrices per launch ----------
__global__ __launch_bounds__(256) void conv3(
    const float* __restrict__ a0, const float* __restrict__ a1, const float* __restrict__ a2,
    unsigned short* __restrict__ o0, unsigned short* __restrict__ o1, unsigned short* __restrict__ o2,
    int count)
{
    const float* in; unsigned short* out;
    if (blockIdx.y == 0) { in = a0; out = o0; }
    else if (blockIdx.y == 1) { in = a1; out = o1; }
    else { in = a2; out = o2; }
    int i = blockIdx.x * 256 + threadIdx.x;
    if (i < count) out[i] = f2bf(in[i]);
}

// ================= CSR build (4 edge-sets via grid.y) =================
__global__ __launch_bounds__(256) void hist4(
    const int* __restrict__ e0, const int* __restrict__ e1,
    const int* __restrict__ e2, const int* __restrict__ e3,
    int* __restrict__ deg, int nE, int n)
{
    const int* srcs[4] = {e0, e1, e2, e3};
    int s = blockIdx.y;
    int e = blockIdx.x * 256 + threadIdx.x;
    if (e < nE) atomicAdd(&deg[(size_t)s * n + srcs[s][e]], 1);
}

// 3-phase exclusive scan over 4 segments of n
__global__ __launch_bounds__(256) void scan_part(
    const int* __restrict__ deg, int* __restrict__ part, int* __restrict__ bsum, int n, int nb)
{
    int s = blockIdx.y;
    int i = blockIdx.x * 256 + threadIdx.x;
    __shared__ int tmp[256];
    int val = (i < n) ? deg[(size_t)s * n + i] : 0;
    tmp[threadIdx.x] = val; __syncthreads();
    for (int o = 1; o < 256; o <<= 1) {
        int t = (threadIdx.x >= o) ? tmp[threadIdx.x - o] : 0;
        __syncthreads(); tmp[threadIdx.x] += t; __syncthreads();
    }
    if (i < n) part[(size_t)s * n + i] = tmp[threadIdx.x] - val;
    if (threadIdx.x == 255) bsum[s * nb + blockIdx.x] = tmp[255];
}
__global__ __launch_bounds__(256) void scan_bsum(int* __restrict__ bsum, int nb)
{
    int s = blockIdx.x;
    __shared__ int tmp[256];
    int val = (threadIdx.x < nb) ? bsum[s * nb + threadIdx.x] : 0;
    tmp[threadIdx.x] = val; __syncthreads();
    for (int o = 1; o < 256; o <<= 1) {
        int t = (threadIdx.x >= o) ? tmp[threadIdx.x - o] : 0;
        __syncthreads(); tmp[threadIdx.x] += t; __syncthreads();
    }
    if (threadIdx.x < nb) bsum[s * nb + threadIdx.x] = tmp[threadIdx.x] - val;
}
__global__ __launch_bounds__(256) void scan_add(
    const int* __restrict__ part, const int* __restrict__ bsum,
    int* __restrict__ rowptr, int* __restrict__ cursor, int n, int nb)
{
    int s = blockIdx.y;
    int i = blockIdx.x * 256 + threadIdx.x;
    if (i < n) {
        int vv = part[(size_t)s * n + i] + bsum[s * nb + blockIdx.x];
        rowptr[(size_t)s * n + i] = vv;
        cursor[(size_t)s * n + i] = vv;
    }
}

__global__ __launch_bounds__(256) void fill4(
    const int* __restrict__ e0, const int* __restrict__ e1,
    const int* __restrict__ e2, const int* __restrict__ e3,
    int* __restrict__ cursor, int* __restrict__ col, int nE, int n)
{
    const int* bases[4] = {e0, e1, e2, e3};
    int s = blockIdx.y;
    int e = blockIdx.x * 256 + threadIdx.x;
    if (e < nE) {
        int p = atomicAdd(&cursor[(size_t)s * n + bases[s][e]], 1);
        col[(size_t)s * nE + p] = bases[s][e + nE];
    }
}

// ================= MFMA Q/K/V projection =================
// One wave = 16 nodes. A-frag: x[node0+lane%16][k], k = ks*32+(lane/16)*8+j.
// B-frag: W[nt*16+lane%16][same k]. D: col=lane&15 (output), row=(lane>>4)*4+reg (node).
static __device__ __forceinline__ short8 pack8(const float* p) {
    float4 a = *(const float4*)p;
    float4 b = *(const float4*)(p + 4);
    short8 v;
    v[0] = (short)f2bf(a.x); v[1] = (short)f2bf(a.y);
    v[2] = (short)f2bf(a.z); v[3] = (short)f2bf(a.w);
    v[4] = (short)f2bf(b.x); v[5] = (short)f2bf(b.y);
    v[6] = (short)f2bf(b.z); v[7] = (short)f2bf(b.w);
    return v;
}

template<int NT, int A, bool BF>
__device__ __forceinline__ void mat_mfma(
    const short8* xf, const unsigned short* W, const float* b,
    void* o, int node0, int r, int kg)
{
    floatx4 acc[NT];
#pragma unroll
    for (int nt = 0; nt < NT; ++nt) {
        float bb = b[nt * 16 + r];
        acc[nt] = (floatx4){bb, bb, bb, bb};
    }
#pragma unroll
    for (int ks = 0; ks < 4; ++ks) {
#pragma unroll
        for (int nt = 0; nt < NT; ++nt) {
            short8 wf = *(const short8*)((const short*)W + (size_t)(nt * 16 + r) * IN_F + ks * 32 + kg * 8);
            acc[nt] = __builtin_amdgcn_mfma_f32_16x16x32_bf16(xf[ks], wf, acc[nt], 0, 0, 0);
        }
    }
#pragma unroll
    for (int nt = 0; nt < NT; ++nt)
#pragma unroll
        for (int reg = 0; reg < 4; ++reg) {
            size_t idx = (size_t)(node0 + kg * 4 + reg) * A + nt * 16 + r;
            if constexpr (BF) ((unsigned short*)o)[idx] = f2bf(acc[nt][reg]);
            else              ((float*)o)[idx] = acc[nt][reg];
        }
}

template<int A>
__global__ __launch_bounds__(256) void qkv_mfma(
    const float* __restrict__ x,
    const unsigned short* __restrict__ Wqb, const float* __restrict__ bq,
    const unsigned short* __restrict__ Wkb, const float* __restrict__ bk,
    const unsigned short* __restrict__ Wvb, const float* __restrict__ bv,
    float* __restrict__ qo, unsigned short* __restrict__ ko, unsigned short* __restrict__ vo,
    int n)
{
    constexpr int NT = A / 16;
    const int wave = threadIdx.x >> 6;
    const int lane = threadIdx.x & 63;
    const int node0 = blockIdx.x * 64 + wave * 16;
    if (node0 >= n) return;
    const int r  = lane & 15;
    const int kg = lane >> 4;

    short8 xf[4];
    const float* xr = x + (size_t)(node0 + r) * IN_F + kg * 8;
#pragma unroll
    for (int ks = 0; ks < 4; ++ks) xf[ks] = pack8(xr + ks * 32);

    mat_mfma<NT, A, false>(xf, Wqb, bq, qo, node0, r, kg);
    mat_mfma<NT, A, true >(xf, Wkb, bk, ko, node0, r, kg);
    mat_mfma<NT, A, true >(xf, Wvb, bv, vo, node0, r, kg);
}

// ---------- online-softmax state merge ----------
static __device__ __forceinline__ void sm_merge(
    float& m0, float& l0, float& ax0, float& ay0,
    float m1, float l1, float ax1, float ay1)
{
    float M = fmaxf(m0, m1);
    float c0 = (l0 > 0.f) ? __expf(m0 - M) : 0.f;
    float c1 = (l1 > 0.f) ? __expf(m1 - M) : 0.f;
    l0 = l0 * c0 + l1 * c1;
    ax0 = ax0 * c0 + ax1 * c1;
    ay0 = ay0 * c0 + ay1 * c1;
    m0 = M;
}

// ================= fused per-node gather (A=128, dk=32), bf16 k/v =================
// One wave per src node; 4 independent softmax states (4 edges in flight).
template<bool ACCUM, bool ELU>
__global__ __launch_bounds__(256) void gat_node128(
    const float* __restrict__ q, const unsigned int* __restrict__ kb,
    const unsigned int* __restrict__ vb,
    const int* __restrict__ rowptr, const int* __restrict__ deg,
    const int* __restrict__ col,
    float* __restrict__ out, float beta, float scale, int n)
{
    constexpr int U = 4;
    int wid  = (blockIdx.x * 256 + threadIdx.x) >> 6;
    int lane = threadIdx.x & 63;
    if (wid >= n) return;
    int start = rowptr[wid], cnt = deg[wid];
    float2 qv = ((const float2*)q)[(size_t)wid * 64 + lane];
    float m[U], l[U], ax[U], ay[U];
#pragma unroll
    for (int u = 0; u < U; ++u) { m[u] = -INFINITY; l[u] = 0.f; ax[u] = 0.f; ay[u] = 0.f; }

    int t = 0;
    for (; t + U <= cnt; t += U) {
        int d[U]; unsigned int kw[U], vw[U];
#pragma unroll
        for (int u = 0; u < U; ++u) d[u] = col[start + t + u];
#pragma unroll
        for (int u = 0; u < U; ++u) {
            kw[u] = kb[(size_t)d[u] * 64 + lane];
            vw[u] = vb[(size_t)d[u] * 64 + lane];
        }
#pragma unroll
        for (int u = 0; u < U; ++u) {
            float2 kv = bf2f2(kw[u]);
            float2 vv = bf2f2(vw[u]);
            float p = qv.x * kv.x + qv.y * kv.y;
            p += __shfl_xor(p, 1);
            p += __shfl_xor(p, 2);
            p += __shfl_xor(p, 4);
            p += __shfl_xor(p, 8);
            float s = p * scale;
            float M = fmaxf(m[u], s);
            float c = __expf(m[u] - M);
            float e = __expf(s - M);
            l[u]  = l[u] * c + e;
            ax[u] = ax[u] * c + e * vv.x;
            ay[u] = ay[u] * c + e * vv.y;
            m[u]  = M;
        }
    }
    for (; t < cnt; ++t) {
        int d = col[start + t];
        float2 kv = bf2f2(kb[(size_t)d * 64 + lane]);
        float2 vv = bf2f2(vb[(size_t)d * 64 + lane]);
        float p = qv.x * kv.x + qv.y * kv.y;
        p += __shfl_xor(p, 1);
        p += __shfl_xor(p, 2);
        p += __shfl_xor(p, 4);
        p += __shfl_xor(p, 8);
        float s = p * scale;
        float M = fmaxf(m[0], s);
        float c = __expf(m[0] - M);
        float e = __expf(s - M);
        l[0]  = l[0] * c + e;
        ax[0] = ax[0] * c + e * vv.x;
        ay[0] = ay[0] * c + e * vv.y;
        m[0]  = M;
    }
    sm_merge(m[0], l[0], ax[0], ay[0], m[1], l[1], ax[1], ay[1]);
    sm_merge(m[2], l[2], ax[2], ay[2], m[3], l[3], ax[3], ay[3]);
    sm_merge(m[0], l[0], ax[0], ay[0], m[2], l[2], ax[2], ay[2]);

    float inv = (l[0] > 0.f) ? 1.f / l[0] : 0.f;
    float2* op = (float2*)out + (size_t)wid * 64 + lane;
    float2 res;
    if constexpr (ACCUM) {
        float2 cur = *op;
        res.x = cur.x + beta * ax[0] * inv;
        res.y = cur.y + beta * ay[0] * inv;
    } else {
        res.x = beta * ax[0] * inv;
        res.y = beta * ay[0] * inv;
    }
    if constexpr (ELU) {
        res.x = res.x > 0.f ? res.x : expm1f(res.x);
        res.y = res.y > 0.f ? res.y : expm1f(res.y);
    }
    *op = res;
}

// ================= fused per-node gather (A=32, dk=8), bf16 k/v =================
// One wave per node; 4 edges in flight (16 lanes each). FINAL: fuse log_softmax.
template<bool ACCUM, bool FINAL>
__global__ __launch_bounds__(256) void gat_node32(
    const float* __restrict__ q, const unsigned int* __restrict__ kb,
    const unsigned int* __restrict__ vb,
    const int* __restrict__ rowptr, const int* __restrict__ deg,
    const int* __restrict__ col,
    float* __restrict__ out, float beta, float scale, int n)
{
    int wid  = (blockIdx.x * 256 + threadIdx.x) >> 6;
    int lane = threadIdx.x & 63;
    if (wid >= n) return;
    int start = rowptr[wid], cnt = deg[wid];
    int g  = lane >> 4;
    int il = lane & 15;
    float2 qv = ((const float2*)q)[(size_t)wid * 16 + il];
    float m = -INFINITY, l = 0.f, ax = 0.f, ay = 0.f;
    for (int t = g; t < cnt; t += 4) {
        int d = col[start + t];
        float2 kv = bf2f2(kb[(size_t)d * 16 + il]);
        float2 vv = bf2f2(vb[(size_t)d * 16 + il]);
        float p = qv.x * kv.x + qv.y * kv.y;
        p += __shfl_xor(p, 1);
        p += __shfl_xor(p, 2);
        float s = p * scale;
        float M = fmaxf(m, s);
        float c = __expf(m - M);
        float e = __expf(s - M);
        l  = l * c + e;
        ax = ax * c + e * vv.x;
        ay = ay * c + e * vv.y;
        m  = M;
    }
#pragma unroll
    for (int off = 16; off <= 32; off <<= 1) {
        float mo  = __shfl_xor(m, off);
        float lo  = __shfl_xor(l, off);
        float axo = __shfl_xor(ax, off);
        float ayo = __shfl_xor(ay, off);
        float M  = fmaxf(m, mo);
        float cA = (l  > 0.f) ? __expf(m  - M) : 0.f;
        float cB = (lo > 0.f) ? __expf(mo - M) : 0.f;
        l  = l * cA + lo * cB;
        ax = ax * cA + axo * cB;
        ay = ay * cA + ayo * cB;
        m  = M;
    }
    if (g == 0) {
        float inv = (l > 0.f) ? 1.f / l : 0.f;
        float2* op = (float2*)out + (size_t)wid * 16 + il;
        float zx, zy;
        if constexpr (ACCUM) {
            float2 cur = *op;
            zx = cur.x + beta * ax * inv;
            zy = cur.y + beta * ay * inv;
        } else {
            zx = beta * ax * inv;
            zy = beta * ay * inv;
        }
        if constexpr (FINAL) {
            // log_softmax over the 32 classes spread across lanes 0..15 (2/lane)
            float mx = fmaxf(zx, zy);
#pragma unroll
            for (int o = 8; o; o >>= 1) mx = fmaxf(mx, __shfl_xor(mx, o));
            float sm = __expf(zx - mx) + __expf(zy - mx);
#pragma unroll
            for (int o = 8; o; o >>= 1) sm += __shfl_xor(sm, o);
            float lse = mx + logf(sm);
            zx -= lse; zy -= lse;
        }
        *op = make_float2(zx, zy);
    }
}

extern "C" void kernel_launch(void* const* d_in, const int* in_sizes, int n_in,
                              void* d_out, int out_size, void* d_ws, size_t ws_size,
                              hipStream_t stream)
{
    const float* x   = (const float*)d_in[0];
    const float* Wq0 = (const float*)d_in[1];
    const float* bq0 = (const float*)d_in[2];
    const float* Wk0 = (const float*)d_in[3];
    const float* bk0 = (const float*)d_in[4];
    const float* Wv0 = (const float*)d_in[5];
    const float* bv0 = (const float*)d_in[6];
    const float* Wq1 = (const float*)d_in[7];
    const float* bq1 = (const float*)d_in[8];
    const float* Wk1 = (const float*)d_in[9];
    const float* bk1 = (const float*)d_in[10];
    const float* Wv1 = (const float*)d_in[11];
    const float* bv1 = (const float*)d_in[12];
    const int* e0 = (const int*)d_in[13];
    const int* e1 = (const int*)d_in[14];
    const int* e2 = (const int*)d_in[15];
    const int* e3 = (const int*)d_in[16];

    char* w = (char*)d_ws;
    float*          q   = (float*)w;          w += (size_t)N_NODES * HID * 4;
    unsigned short* kb  = (unsigned short*)w; w += (size_t)N_NODES * HID * 2;
    unsigned short* vb  = (unsigned short*)w; w += (size_t)N_NODES * HID * 2;
    float*          acc = (float*)w;          w += (size_t)N_NODES * HID * 4;  // h after ELU
    float*          lg  = (float*)w;          w += (size_t)N_NODES * CLS * 4;
    int* deg    = (int*)w; w += (size_t)4 * N_NODES * 4;
    int* rowptr = (int*)w; w += (size_t)4 * N_NODES * 4;
    int* cursor = (int*)w; w += (size_t)4 * N_NODES * 4;
    int* part   = (int*)w; w += (size_t)4 * N_NODES * 4;
    int* bsum   = (int*)w; w += (size_t)4 * 256 * 4;
    int* col    = (int*)w; w += (size_t)4 * N_EDGES * 4;
    unsigned short* wq0b = (unsigned short*)w; w += (size_t)2 * HID * IN_F * 2;
    unsigned short* wk0b = (unsigned short*)w; w += (size_t)2 * HID * IN_F * 2;
    unsigned short* wv0b = (unsigned short*)w; w += (size_t)2 * HID * IN_F * 2;
    unsigned short* wq1b = (unsigned short*)w; w += (size_t)2 * CLS * IN_F * 2;
    unsigned short* wk1b = (unsigned short*)w; w += (size_t)2 * CLS * IN_F * 2;
    unsigned short* wv1b = (unsigned short*)w; w += (size_t)2 * CLS * IN_F * 2;

    float* out = (float*)d_out;
    const int EB = (N_EDGES + 255) / 256;
    const int NBL = (N_NODES + 255) / 256;     // 196
    const int NB  = (N_NODES + 3) / 4;         // gat: 4 waves / block
    const int QB  = (N_NODES / 16 + 3) / 4;    // qkv: 4 waves (16 nodes) / block

    // ---------- weights -> bf16 ----------
    const int W0 = 2 * HID * IN_F, W1 = 2 * CLS * IN_F;
    conv3<<<dim3((W0 + 255) / 256, 3), 256, 0, stream>>>(Wq0, Wk0, Wv0, wq0b, wk0b, wv0b, W0);
    conv3<<<dim3((W1 + 255) / 256, 3), 256, 0, stream>>>(Wq1, Wk1, Wv1, wq1b, wk1b, wv1b, W1);

    // ---------- build 4 CSRs ----------
    hipMemsetAsync(deg, 0, (size_t)4 * N_NODES * 4, stream);
    hist4<<<dim3(EB, 4), 256, 0, stream>>>(e0, e1, e2, e3, deg, N_EDGES, N_NODES);
    scan_part<<<dim3(NBL, 4), 256, 0, stream>>>(deg, part, bsum, N_NODES, NBL);
    scan_bsum<<<4, 256, 0, stream>>>(bsum, NBL);
    scan_add<<<dim3(NBL, 4), 256, 0, stream>>>(part, bsum, rowptr, cursor, N_NODES, NBL);
    fill4<<<dim3(EB, 4), 256, 0, stream>>>(e0, e1, e2, e3, cursor, col, N_EDGES, N_NODES);

    // ================= layer 0 (A=128, dk=32) =================
    for (int hop = 0; hop < 2; ++hop) {
        qkv_mfma<HID><<<QB, 256, 0, stream>>>(
            x,
            wq0b + (size_t)hop * HID * IN_F, bq0 + (size_t)hop * HID,
            wk0b + (size_t)hop * HID * IN_F, bk0 + (size_t)hop * HID,
            wv0b + (size_t)hop * HID * IN_F, bv0 + (size_t)hop * HID,
            q, kb, vb, N_NODES);
        const int* rp = rowptr + (size_t)hop * N_NODES;
        const int* dg = deg + (size_t)hop * N_NODES;
        const int* cl = col + (size_t)hop * N_EDGES;
        if (hop == 0)
            gat_node128<false, false><<<NB, 256, 0, stream>>>(
                q, (const unsigned int*)kb, (const unsigned int*)vb, rp, dg, cl,
                acc, 1.0f, 1.f / sqrtf(32.f), N_NODES);
        else
            gat_node128<true, true><<<NB, 256, 0, stream>>>(
                q, (const unsigned int*)kb, (const unsigned int*)vb, rp, dg, cl,
                acc, 0.5f, 1.f / sqrtf(32.f), N_NODES);
    }

    // ================= layer 1 (A=32, dk=8) =================
    for (int hop = 0; hop < 2; ++hop) {
        qkv_mfma<CLS><<<QB, 256, 0, stream>>>(
            acc,
            wq1b + (size_t)hop * CLS * IN_F, bq1 + (size_t)hop * CLS,
            wk1b + (size_t)hop * CLS * IN_F, bk1 + (size_t)hop * CLS,
            wv1b + (size_t)hop * CLS * IN_F, bv1 + (size_t)hop * CLS,
            q, kb, vb, N_NODES);
        const int* rp = rowptr + (size_t)(2 + hop) * N_NODES;
        const int* dg = deg + (size_t)(2 + hop) * N_NODES;
        const int* cl = col + (size_t)(2 + hop) * N_EDGES;
        if (hop == 0)
            gat_node32<false, false><<<NB, 256, 0, stream>>>(
                q, (const unsigned int*)kb, (const unsigned int*)vb, rp, dg, cl,
                lg, 1.0f, 1.f / sqrtf(8.f), N_NODES);
        else
            gat_node32<true, true><<<NB, 256, 0, stream>>>(
                q, (const unsigned int*)kb, (const unsigned int*)vb, rp, dg, cl,
                lg, 0.5f, 1.f / sqrtf(8.f), N_NODES);
    }
    // lg holds final log-softmax for hop==1 path; copy row-block to out
    hipMemcpyAsync(out, lg, (size_t)N_NODES * CLS * 4, hipMemcpyDeviceToDevice, stream);
}

// Round 5
// 441.460 us; speedup vs baseline: 10.5290x; 1.7101x over previous
//
#include <hip/hip_runtime.h>
#include <hip/hip_bf16.h>
#include <math.h>

#define N_NODES 50000
#define N_EDGES 800000
#define IN_F    128
#define HID     128
#define CLS     32
#define NHEAD   4
#define NBUCK   196        // ceil(N_NODES / 256)

typedef __attribute__((ext_vector_type(8))) short  short8;
typedef __attribute__((ext_vector_type(4))) float  floatx4;

// ---------- f32 -> bf16 (RNE) ----------
static __device__ __forceinline__ unsigned short f2bf(float f) {
    unsigned int u = __float_as_uint(f);
    return (unsigned short)((u + 0x7fffu + ((u >> 16) & 1u)) >> 16);
}
static __device__ __forceinline__ float2 bf2f2(unsigned int u) {
    return make_float2(__uint_as_float(u << 16), __uint_as_float(u & 0xffff0000u));
}

// ---------- weight conversion: 3 matrices per launch ----------
__global__ __launch_bounds__(256) void conv3(
    const float* __restrict__ a0, const float* __restrict__ a1, const float* __restrict__ a2,
    unsigned short* __restrict__ o0, unsigned short* __restrict__ o1, unsigned short* __restrict__ o2,
    int count)
{
    const float* in; unsigned short* out;
    if (blockIdx.y == 0) { in = a0; out = o0; }
    else if (blockIdx.y == 1) { in = a1; out = o1; }
    else { in = a2; out = o2; }
    int i = blockIdx.x * 256 + threadIdx.x;
    if (i < count) out[i] = f2bf(in[i]);
}

// ================= CSR build: 2-pass coarse-bucket counting sort =================
// bucket = src >> 8 (256 nodes per bucket, NBUCK buckets)

__global__ __launch_bounds__(256) void bucket_hist(
    const int* __restrict__ e0, const int* __restrict__ e1,
    const int* __restrict__ e2, const int* __restrict__ e3,
    int* __restrict__ bcnt, int nE)
{
    const int s = blockIdx.y;
    const int* ep = (s == 0) ? e0 : (s == 1) ? e1 : (s == 2) ? e2 : e3;
    __shared__ int h[NBUCK];
    for (int i = threadIdx.x; i < NBUCK; i += 256) h[i] = 0;
    __syncthreads();
    for (int e = blockIdx.x * 256 + threadIdx.x; e < nE; e += gridDim.x * 256)
        atomicAdd(&h[ep[e] >> 8], 1);
    __syncthreads();
    for (int i = threadIdx.x; i < NBUCK; i += 256)
        if (h[i]) atomicAdd(&bcnt[s * NBUCK + i], h[i]);
}

// per-set exclusive scan of NBUCK bucket counts -> bbase (NBUCK+1) + bcur copy
__global__ __launch_bounds__(256) void bucket_scan(
    const int* __restrict__ bcnt, int* __restrict__ bbase, int* __restrict__ bcur)
{
    int s = blockIdx.x;
    __shared__ int tmp[256];
    int v = (threadIdx.x < NBUCK) ? bcnt[s * NBUCK + threadIdx.x] : 0;
    tmp[threadIdx.x] = v; __syncthreads();
    for (int o = 1; o < 256; o <<= 1) {
        int t = (threadIdx.x >= o) ? tmp[threadIdx.x - o] : 0;
        __syncthreads(); tmp[threadIdx.x] += t; __syncthreads();
    }
    int excl = tmp[threadIdx.x] - v;
    if (threadIdx.x < NBUCK) {
        bbase[s * (NBUCK + 1) + threadIdx.x] = excl;
        bcur[s * NBUCK + threadIdx.x] = excl;
    }
    if (threadIdx.x == NBUCK - 1)
        bbase[s * (NBUCK + 1) + NBUCK] = excl + v;
}

// pass 1: tile-chunked scatter of (src,dst) pairs into bucket regions
#define TILE 8192
__global__ __launch_bounds__(256) void pass1_scatter(
    const int* __restrict__ e0, const int* __restrict__ e1,
    const int* __restrict__ e2, const int* __restrict__ e3,
    int* __restrict__ bcur, int2* __restrict__ pairs, int nE)
{
    const int s = blockIdx.y;
    const int* ep = (s == 0) ? e0 : (s == 1) ? e1 : (s == 2) ? e2 : e3;
    const int tile0 = blockIdx.x * TILE;
    __shared__ int hist[NBUCK], base[NBUCK], cur[NBUCK];
    for (int i = threadIdx.x; i < NBUCK; i += 256) { hist[i] = 0; cur[i] = 0; }
    __syncthreads();
    for (int i = threadIdx.x; i < TILE; i += 256) {
        int e = tile0 + i;
        if (e < nE) atomicAdd(&hist[ep[e] >> 8], 1);
    }
    __syncthreads();
    for (int i = threadIdx.x; i < NBUCK; i += 256)
        base[i] = hist[i] ? atomicAdd(&bcur[s * NBUCK + i], hist[i]) : 0;
    __syncthreads();
    int2* pp = pairs + (size_t)s * nE;
    for (int i = threadIdx.x; i < TILE; i += 256) {
        int e = tile0 + i;
        if (e < nE) {
            int src = ep[e], dst = ep[e + nE];
            int b = src >> 8;
            int r = atomicAdd(&cur[b], 1);
            pp[base[b] + r] = make_int2(src, dst);
        }
    }
}

// pass 2: per-bucket exact placement; also emits rowptr/deg
__global__ __launch_bounds__(256) void pass2_place(
    const int2* __restrict__ pairs, const int* __restrict__ bbase,
    int* __restrict__ rowptr, int* __restrict__ deg, int* __restrict__ col,
    int nE, int n)
{
    const int s = blockIdx.y, b = blockIdx.x;
    const int base0 = bbase[s * (NBUCK + 1) + b];
    const int ecnt  = bbase[s * (NBUCK + 1) + b + 1] - base0;
    const int2* pp = pairs + (size_t)s * nE + base0;
    __shared__ int hist[256], cur[256];
    hist[threadIdx.x] = 0;
    __syncthreads();
    for (int i = threadIdx.x; i < ecnt; i += 256)
        atomicAdd(&hist[pp[i].x & 255], 1);
    __syncthreads();
    int v = hist[threadIdx.x];
    cur[threadIdx.x] = v; __syncthreads();
    for (int o = 1; o < 256; o <<= 1) {
        int t = (threadIdx.x >= o) ? cur[threadIdx.x - o] : 0;
        __syncthreads(); cur[threadIdx.x] += t; __syncthreads();
    }
    int excl = cur[threadIdx.x] - v;
    int node = b * 256 + threadIdx.x;
    if (node < n) {
        rowptr[(size_t)s * n + node] = base0 + excl;
        deg[(size_t)s * n + node] = v;
    }
    __syncthreads();
    cur[threadIdx.x] = excl;
    __syncthreads();
    int* colp = col + (size_t)s * nE + base0;
    for (int i = threadIdx.x; i < ecnt; i += 256) {
        int2 pr = pp[i];
        int r = atomicAdd(&cur[pr.x & 255], 1);
        colp[r] = pr.y;
    }
}

// ================= MFMA Q/K/V projection =================
static __device__ __forceinline__ short8 pack8(const float* p) {
    float4 a = *(const float4*)p;
    float4 b = *(const float4*)(p + 4);
    short8 v;
    v[0] = (short)f2bf(a.x); v[1] = (short)f2bf(a.y);
    v[2] = (short)f2bf(a.z); v[3] = (short)f2bf(a.w);
    v[4] = (short)f2bf(b.x); v[5] = (short)f2bf(b.y);
    v[6] = (short)f2bf(b.z); v[7] = (short)f2bf(b.w);
    return v;
}

template<int NT, int A, bool BF>
__device__ __forceinline__ void mat_mfma(
    const short8* xf, const unsigned short* W, const float* b,
    void* o, int node0, int r, int kg)
{
    floatx4 acc[NT];
#pragma unroll
    for (int nt = 0; nt < NT; ++nt) {
        float bb = b[nt * 16 + r];
        acc[nt] = (floatx4){bb, bb, bb, bb};
    }
#pragma unroll
    for (int ks = 0; ks < 4; ++ks) {
#pragma unroll
        for (int nt = 0; nt < NT; ++nt) {
            short8 wf = *(const short8*)((const short*)W + (size_t)(nt * 16 + r) * IN_F + ks * 32 + kg * 8);
            acc[nt] = __builtin_amdgcn_mfma_f32_16x16x32_bf16(xf[ks], wf, acc[nt], 0, 0, 0);
        }
    }
#pragma unroll
    for (int nt = 0; nt < NT; ++nt)
#pragma unroll
        for (int reg = 0; reg < 4; ++reg) {
            size_t idx = (size_t)(node0 + kg * 4 + reg) * A + nt * 16 + r;
            if constexpr (BF) ((unsigned short*)o)[idx] = f2bf(acc[nt][reg]);
            else              ((float*)o)[idx] = acc[nt][reg];
        }
}

template<int A>
__global__ __launch_bounds__(256) void qkv_mfma(
    const float* __restrict__ x,
    const unsigned short* __restrict__ Wqb, const float* __restrict__ bq,
    const unsigned short* __restrict__ Wkb, const float* __restrict__ bk,
    const unsigned short* __restrict__ Wvb, const float* __restrict__ bv,
    float* __restrict__ qo, unsigned short* __restrict__ ko, unsigned short* __restrict__ vo,
    int n)
{
    constexpr int NT = A / 16;
    const int wave = threadIdx.x >> 6;
    const int lane = threadIdx.x & 63;
    const int node0 = blockIdx.x * 64 + wave * 16;
    if (node0 >= n) return;
    const int r  = lane & 15;
    const int kg = lane >> 4;

    short8 xf[4];
    const float* xr = x + (size_t)(node0 + r) * IN_F + kg * 8;
#pragma unroll
    for (int ks = 0; ks < 4; ++ks) xf[ks] = pack8(xr + ks * 32);

    mat_mfma<NT, A, false>(xf, Wqb, bq, qo, node0, r, kg);
    mat_mfma<NT, A, true >(xf, Wkb, bk, ko, node0, r, kg);
    mat_mfma<NT, A, true >(xf, Wvb, bv, vo, node0, r, kg);
}

// ---------- online-softmax state merge ----------
static __device__ __forceinline__ void sm_merge(
    float& m0, float& l0, float& ax0, float& ay0,
    float m1, float l1, float ax1, float ay1)
{
    float M = fmaxf(m0, m1);
    float c0 = (l0 > 0.f) ? __expf(m0 - M) : 0.f;
    float c1 = (l1 > 0.f) ? __expf(m1 - M) : 0.f;
    l0 = l0 * c0 + l1 * c1;
    ax0 = ax0 * c0 + ax1 * c1;
    ay0 = ay0 * c0 + ay1 * c1;
    m0 = M;
}

// ================= fused per-node gather (A=128, dk=32), bf16 k/v =================
template<bool ACCUM, bool ELU>
__global__ __launch_bounds__(256) void gat_node128(
    const float* __restrict__ q, const unsigned int* __restrict__ kb,
    const unsigned int* __restrict__ vb,
    const int* __restrict__ rowptr, const int* __restrict__ deg,
    const int* __restrict__ col,
    float* __restrict__ out, float beta, float scale, int n)
{
    constexpr int U = 4;
    int wid  = (blockIdx.x * 256 + threadIdx.x) >> 6;
    int lane = threadIdx.x & 63;
    if (wid >= n) return;
    int start = rowptr[wid], cnt = deg[wid];
    float2 qv = ((const float2*)q)[(size_t)wid * 64 + lane];
    float m[U], l[U], ax[U], ay[U];
#pragma unroll
    for (int u = 0; u < U; ++u) { m[u] = -INFINITY; l[u] = 0.f; ax[u] = 0.f; ay[u] = 0.f; }

    int t = 0;
    for (; t + U <= cnt; t += U) {
        int d[U]; unsigned int kw[U], vw[U];
#pragma unroll
        for (int u = 0; u < U; ++u) d[u] = col[start + t + u];
#pragma unroll
        for (int u = 0; u < U; ++u) {
            kw[u] = kb[(size_t)d[u] * 64 + lane];
            vw[u] = vb[(size_t)d[u] * 64 + lane];
        }
#pragma unroll
        for (int u = 0; u < U; ++u) {
            float2 kv = bf2f2(kw[u]);
            float2 vv = bf2f2(vw[u]);
            float p = qv.x * kv.x + qv.y * kv.y;
            p += __shfl_xor(p, 1);
            p += __shfl_xor(p, 2);
            p += __shfl_xor(p, 4);
            p += __shfl_xor(p, 8);
            float s = p * scale;
            float M = fmaxf(m[u], s);
            float c = __expf(m[u] - M);
            float e = __expf(s - M);
            l[u]  = l[u] * c + e;
            ax[u] = ax[u] * c + e * vv.x;
            ay[u] = ay[u] * c + e * vv.y;
            m[u]  = M;
        }
    }
    for (; t < cnt; ++t) {
        int d = col[start + t];
        float2 kv = bf2f2(kb[(size_t)d * 64 + lane]);
        float2 vv = bf2f2(vb[(size_t)d * 64 + lane]);
        float p = qv.x * kv.x + qv.y * kv.y;
        p += __shfl_xor(p, 1);
        p += __shfl_xor(p, 2);
        p += __shfl_xor(p, 4);
        p += __shfl_xor(p, 8);
        float s = p * scale;
        float M = fmaxf(m[0], s);
        float c = __expf(m[0] - M);
        float e = __expf(s - M);
        l[0]  = l[0] * c + e;
        ax[0] = ax[0] * c + e * vv.x;
        ay[0] = ay[0] * c + e * vv.y;
        m[0]  = M;
    }
    sm_merge(m[0], l[0], ax[0], ay[0], m[1], l[1], ax[1], ay[1]);
    sm_merge(m[2], l[2], ax[2], ay[2], m[3], l[3], ax[3], ay[3]);
    sm_merge(m[0], l[0], ax[0], ay[0], m[2], l[2], ax[2], ay[2]);

    float inv = (l[0] > 0.f) ? 1.f / l[0] : 0.f;
    float2* op = (float2*)out + (size_t)wid * 64 + lane;
    float2 res;
    if constexpr (ACCUM) {
        float2 cur = *op;
        res.x = cur.x + beta * ax[0] * inv;
        res.y = cur.y + beta * ay[0] * inv;
    } else {
        res.x = beta * ax[0] * inv;
        res.y = beta * ay[0] * inv;
    }
    if constexpr (ELU) {
        res.x = res.x > 0.f ? res.x : expm1f(res.x);
        res.y = res.y > 0.f ? res.y : expm1f(res.y);
    }
    *op = res;
}

// ================= fused per-node gather (A=32, dk=8), bf16 k/v =================
// prev: accumulator input (hop-0 result); outp: output buffer (may differ).
template<bool ACCUM, bool FINAL>
__global__ __launch_bounds__(256) void gat_node32(
    const float* __restrict__ q, const unsigned int* __restrict__ kb,
    const unsigned int* __restrict__ vb,
    const int* __restrict__ rowptr, const int* __restrict__ deg,
    const int* __restrict__ col,
    const float* __restrict__ prev, float* __restrict__ outp,
    float beta, float scale, int n)
{
    int wid  = (blockIdx.x * 256 + threadIdx.x) >> 6;
    int lane = threadIdx.x & 63;
    if (wid >= n) return;
    int start = rowptr[wid], cnt = deg[wid];
    int g  = lane >> 4;
    int il = lane & 15;
    float2 qv = ((const float2*)q)[(size_t)wid * 16 + il];
    float m = -INFINITY, l = 0.f, ax = 0.f, ay = 0.f;
    for (int t = g; t < cnt; t += 4) {
        int d = col[start + t];
        float2 kv = bf2f2(kb[(size_t)d * 16 + il]);
        float2 vv = bf2f2(vb[(size_t)d * 16 + il]);
        float p = qv.x * kv.x + qv.y * kv.y;
        p += __shfl_xor(p, 1);
        p += __shfl_xor(p, 2);
        float s = p * scale;
        float M = fmaxf(m, s);
        float c = __expf(m - M);
        float e = __expf(s - M);
        l  = l * c + e;
        ax = ax * c + e * vv.x;
        ay = ay * c + e * vv.y;
        m  = M;
    }
#pragma unroll
    for (int off = 16; off <= 32; off <<= 1) {
        float mo  = __shfl_xor(m, off);
        float lo  = __shfl_xor(l, off);
        float axo = __shfl_xor(ax, off);
        float ayo = __shfl_xor(ay, off);
        float M  = fmaxf(m, mo);
        float cA = (l  > 0.f) ? __expf(m  - M) : 0.f;
        float cB = (lo > 0.f) ? __expf(mo - M) : 0.f;
        l  = l * cA + lo * cB;
        ax = ax * cA + axo * cB;
        ay = ay * cA + ayo * cB;
        m  = M;
    }
    if (g == 0) {
        float inv = (l > 0.f) ? 1.f / l : 0.f;
        float zx, zy;
        if constexpr (ACCUM) {
            float2 cur = ((const float2*)prev)[(size_t)wid * 16 + il];
            zx = cur.x + beta * ax * inv;
            zy = cur.y + beta * ay * inv;
        } else {
            zx = beta * ax * inv;
            zy = beta * ay * inv;
        }
        if constexpr (FINAL) {
            float mx = fmaxf(zx, zy);
#pragma unroll
            for (int o = 8; o; o >>= 1) mx = fmaxf(mx, __shfl_xor(mx, o));
            float sm = __expf(zx - mx) + __expf(zy - mx);
#pragma unroll
            for (int o = 8; o; o >>= 1) sm += __shfl_xor(sm, o);
            float lse = mx + logf(sm);
            zx -= lse; zy -= lse;
        }
        ((float2*)outp)[(size_t)wid * 16 + il] = make_float2(zx, zy);
    }
}

extern "C" void kernel_launch(void* const* d_in, const int* in_sizes, int n_in,
                              void* d_out, int out_size, void* d_ws, size_t ws_size,
                              hipStream_t stream)
{
    const float* x   = (const float*)d_in[0];
    const float* Wq0 = (const float*)d_in[1];
    const float* bq0 = (const float*)d_in[2];
    const float* Wk0 = (const float*)d_in[3];
    const float* bk0 = (const float*)d_in[4];
    const float* Wv0 = (const float*)d_in[5];
    const float* bv0 = (const float*)d_in[6];
    const float* Wq1 = (const float*)d_in[7];
    const float* bq1 = (const float*)d_in[8];
    const float* Wk1 = (const float*)d_in[9];
    const float* bk1 = (const float*)d_in[10];
    const float* Wv1 = (const float*)d_in[11];
    const float* bv1 = (const float*)d_in[12];
    const int* e0 = (const int*)d_in[13];
    const int* e1 = (const int*)d_in[14];
    const int* e2 = (const int*)d_in[15];
    const int* e3 = (const int*)d_in[16];

    char* w = (char*)d_ws;
    float*          q   = (float*)w;          w += (size_t)N_NODES * HID * 4;
    unsigned short* kb  = (unsigned short*)w; w += (size_t)N_NODES * HID * 2;
    unsigned short* vb  = (unsigned short*)w; w += (size_t)N_NODES * HID * 2;
    float*          acc = (float*)w;          w += (size_t)N_NODES * HID * 4;  // h after ELU
    float*          lg  = (float*)w;          w += (size_t)N_NODES * CLS * 4;
    int* deg    = (int*)w; w += (size_t)4 * N_NODES * 4;
    int* rowptr = (int*)w; w += (size_t)4 * N_NODES * 4;
    int* col    = (int*)w; w += (size_t)4 * N_EDGES * 4;
    int* bcnt   = (int*)w; w += (size_t)4 * NBUCK * 4;
    int* bbase  = (int*)w; w += (size_t)4 * (NBUCK + 1) * 4;
    int* bcur   = (int*)w; w += (size_t)4 * NBUCK * 4;
    unsigned short* wq0b = (unsigned short*)w; w += (size_t)2 * HID * IN_F * 2;
    unsigned short* wk0b = (unsigned short*)w; w += (size_t)2 * HID * IN_F * 2;
    unsigned short* wv0b = (unsigned short*)w; w += (size_t)2 * HID * IN_F * 2;
    unsigned short* wq1b = (unsigned short*)w; w += (size_t)2 * CLS * IN_F * 2;
    unsigned short* wk1b = (unsigned short*)w; w += (size_t)2 * CLS * IN_F * 2;
    unsigned short* wv1b = (unsigned short*)w; w += (size_t)2 * CLS * IN_F * 2;

    // pairs buffer (25.6 MB) aliases q — only live during CSR build, before any qkv
    int2* pairs = (int2*)q;

    float* out = (float*)d_out;
    const int NB = (N_NODES + 3) / 4;          // gat: 4 waves / block
    const int QB = (N_NODES / 16 + 3) / 4;     // qkv: 4 waves (16 nodes) / block

    // ---------- weights -> bf16 ----------
    const int W0 = 2 * HID * IN_F, W1 = 2 * CLS * IN_F;
    conv3<<<dim3((W0 + 255) / 256, 3), 256, 0, stream>>>(Wq0, Wk0, Wv0, wq0b, wk0b, wv0b, W0);
    conv3<<<dim3((W1 + 255) / 256, 3), 256, 0, stream>>>(Wq1, Wk1, Wv1, wq1b, wk1b, wv1b, W1);

    // ---------- build 4 CSRs (bucket counting sort) ----------
    hipMemsetAsync(bcnt, 0, (size_t)4 * NBUCK * 4, stream);
    bucket_hist<<<dim3(256, 4), 256, 0, stream>>>(e0, e1, e2, e3, bcnt, N_EDGES);
    bucket_scan<<<4, 256, 0, stream>>>(bcnt, bbase, bcur);
    pass1_scatter<<<dim3((N_EDGES + TILE - 1) / TILE, 4), 256, 0, stream>>>(
        e0, e1, e2, e3, bcur, pairs, N_EDGES);
    pass2_place<<<dim3(NBUCK, 4), 256, 0, stream>>>(
        pairs, bbase, rowptr, deg, col, N_EDGES, N_NODES);

    // ================= layer 0 (A=128, dk=32) =================
    for (int hop = 0; hop < 2; ++hop) {
        qkv_mfma<HID><<<QB, 256, 0, stream>>>(
            x,
            wq0b + (size_t)hop * HID * IN_F, bq0 + (size_t)hop * HID,
            wk0b + (size_t)hop * HID * IN_F, bk0 + (size_t)hop * HID,
            wv0b + (size_t)hop * HID * IN_F, bv0 + (size_t)hop * HID,
            q, kb, vb, N_NODES);
        const int* rp = rowptr + (size_t)hop * N_NODES;
        const int* dg = deg + (size_t)hop * N_NODES;
        const int* cl = col + (size_t)hop * N_EDGES;
        if (hop == 0)
            gat_node128<false, false><<<NB, 256, 0, stream>>>(
                q, (const unsigned int*)kb, (const unsigned int*)vb, rp, dg, cl,
                acc, 1.0f, 1.f / sqrtf(32.f), N_NODES);
        else
            gat_node128<true, true><<<NB, 256, 0, stream>>>(
                q, (const unsigned int*)kb, (const unsigned int*)vb, rp, dg, cl,
                acc, 0.5f, 1.f / sqrtf(32.f), N_NODES);
    }

    // ================= layer 1 (A=32, dk=8) =================
    for (int hop = 0; hop < 2; ++hop) {
        qkv_mfma<CLS><<<QB, 256, 0, stream>>>(
            acc,
            wq1b + (size_t)hop * CLS * IN_F, bq1 + (size_t)hop * CLS,
            wk1b + (size_t)hop * CLS * IN_F, bk1 + (size_t)hop * CLS,
            wv1b + (size_t)hop * CLS * IN_F, bv1 + (size_t)hop * CLS,
            q, kb, vb, N_NODES);
        const int* rp = rowptr + (size_t)(2 + hop) * N_NODES;
        const int* dg = deg + (size_t)(2 + hop) * N_NODES;
        const int* cl = col + (size_t)(2 + hop) * N_EDGES;
        if (hop == 0)
            gat_node32<false, false><<<NB, 256, 0, stream>>>(
                q, (const unsigned int*)kb, (const unsigned int*)vb, rp, dg, cl,
                nullptr, lg, 1.0f, 1.f / sqrtf(8.f), N_NODES);
        else
            gat_node32<true, true><<<NB, 256, 0, stream>>>(
                q, (const unsigned int*)kb, (const unsigned int*)vb, rp, dg, cl,
                lg, out, 0.5f, 1.f / sqrtf(8.f), N_NODES);
    }
}

// Round 6
// 410.866 us; speedup vs baseline: 11.3131x; 1.0745x over previous
//
#include <hip/hip_runtime.h>
#include <hip/hip_bf16.h>
#include <math.h>

#define N_NODES 50000
#define N_EDGES 800000
#define IN_F    128
#define HID     128
#define CLS     32
#define NHEAD   4
#define NBUCK   196        // ceil(N_NODES / 256)

typedef __attribute__((ext_vector_type(8))) short  short8;
typedef __attribute__((ext_vector_type(4))) float  floatx4;

// ---------- f32 -> bf16 (RNE) ----------
static __device__ __forceinline__ unsigned short f2bf(float f) {
    unsigned int u = __float_as_uint(f);
    return (unsigned short)((u + 0x7fffu + ((u >> 16) & 1u)) >> 16);
}
static __device__ __forceinline__ float2 bf2f2(unsigned int u) {
    return make_float2(__uint_as_float(u << 16), __uint_as_float(u & 0xffff0000u));
}

// ---------- weight conversion: 3 matrices per launch ----------
__global__ __launch_bounds__(256) void conv3(
    const float* __restrict__ a0, const float* __restrict__ a1, const float* __restrict__ a2,
    unsigned short* __restrict__ o0, unsigned short* __restrict__ o1, unsigned short* __restrict__ o2,
    int count)
{
    const float* in; unsigned short* out;
    if (blockIdx.y == 0) { in = a0; out = o0; }
    else if (blockIdx.y == 1) { in = a1; out = o1; }
    else { in = a2; out = o2; }
    int i = blockIdx.x * 256 + threadIdx.x;
    if (i < count) out[i] = f2bf(in[i]);
}

// ================= CSR build: 2-pass coarse-bucket counting sort =================
__global__ __launch_bounds__(256) void bucket_hist(
    const int* __restrict__ e0, const int* __restrict__ e1,
    const int* __restrict__ e2, const int* __restrict__ e3,
    int* __restrict__ bcnt, int nE)
{
    const int s = blockIdx.y;
    const int* ep = (s == 0) ? e0 : (s == 1) ? e1 : (s == 2) ? e2 : e3;
    __shared__ int h[NBUCK];
    for (int i = threadIdx.x; i < NBUCK; i += 256) h[i] = 0;
    __syncthreads();
    for (int e = blockIdx.x * 256 + threadIdx.x; e < nE; e += gridDim.x * 256)
        atomicAdd(&h[ep[e] >> 8], 1);
    __syncthreads();
    for (int i = threadIdx.x; i < NBUCK; i += 256)
        if (h[i]) atomicAdd(&bcnt[s * NBUCK + i], h[i]);
}

__global__ __launch_bounds__(256) void bucket_scan(
    const int* __restrict__ bcnt, int* __restrict__ bbase, int* __restrict__ bcur)
{
    int s = blockIdx.x;
    __shared__ int tmp[256];
    int v = (threadIdx.x < NBUCK) ? bcnt[s * NBUCK + threadIdx.x] : 0;
    tmp[threadIdx.x] = v; __syncthreads();
    for (int o = 1; o < 256; o <<= 1) {
        int t = (threadIdx.x >= o) ? tmp[threadIdx.x - o] : 0;
        __syncthreads(); tmp[threadIdx.x] += t; __syncthreads();
    }
    int excl = tmp[threadIdx.x] - v;
    if (threadIdx.x < NBUCK) {
        bbase[s * (NBUCK + 1) + threadIdx.x] = excl;
        bcur[s * NBUCK + threadIdx.x] = excl;
    }
    if (threadIdx.x == NBUCK - 1)
        bbase[s * (NBUCK + 1) + NBUCK] = excl + v;
}

#define TILE 8192
__global__ __launch_bounds__(256) void pass1_scatter(
    const int* __restrict__ e0, const int* __restrict__ e1,
    const int* __restrict__ e2, const int* __restrict__ e3,
    int* __restrict__ bcur, int2* __restrict__ pairs, int nE)
{
    const int s = blockIdx.y;
    const int* ep = (s == 0) ? e0 : (s == 1) ? e1 : (s == 2) ? e2 : e3;
    const int tile0 = blockIdx.x * TILE;
    __shared__ int hist[NBUCK], base[NBUCK], cur[NBUCK];
    for (int i = threadIdx.x; i < NBUCK; i += 256) { hist[i] = 0; cur[i] = 0; }
    __syncthreads();
    for (int i = threadIdx.x; i < TILE; i += 256) {
        int e = tile0 + i;
        if (e < nE) atomicAdd(&hist[ep[e] >> 8], 1);
    }
    __syncthreads();
    for (int i = threadIdx.x; i < NBUCK; i += 256)
        base[i] = hist[i] ? atomicAdd(&bcur[s * NBUCK + i], hist[i]) : 0;
    __syncthreads();
    int2* pp = pairs + (size_t)s * nE;
    for (int i = threadIdx.x; i < TILE; i += 256) {
        int e = tile0 + i;
        if (e < nE) {
            int src = ep[e], dst = ep[e + nE];
            int b = src >> 8;
            int r = atomicAdd(&cur[b], 1);
            pp[base[b] + r] = make_int2(src, dst);
        }
    }
}

__global__ __launch_bounds__(256) void pass2_place(
    const int2* __restrict__ pairs, const int* __restrict__ bbase,
    int* __restrict__ rowptr, int* __restrict__ deg, int* __restrict__ col,
    int nE, int n)
{
    const int s = blockIdx.y, b = blockIdx.x;
    const int base0 = bbase[s * (NBUCK + 1) + b];
    const int ecnt  = bbase[s * (NBUCK + 1) + b + 1] - base0;
    const int2* pp = pairs + (size_t)s * nE + base0;
    __shared__ int hist[256], cur[256];
    hist[threadIdx.x] = 0;
    __syncthreads();
    for (int i = threadIdx.x; i < ecnt; i += 256)
        atomicAdd(&hist[pp[i].x & 255], 1);
    __syncthreads();
    int v = hist[threadIdx.x];
    cur[threadIdx.x] = v; __syncthreads();
    for (int o = 1; o < 256; o <<= 1) {
        int t = (threadIdx.x >= o) ? cur[threadIdx.x - o] : 0;
        __syncthreads(); cur[threadIdx.x] += t; __syncthreads();
    }
    int excl = cur[threadIdx.x] - v;
    int node = b * 256 + threadIdx.x;
    if (node < n) {
        rowptr[(size_t)s * n + node] = base0 + excl;
        deg[(size_t)s * n + node] = v;
    }
    __syncthreads();
    cur[threadIdx.x] = excl;
    __syncthreads();
    int* colp = col + (size_t)s * nE + base0;
    for (int i = threadIdx.x; i < ecnt; i += 256) {
        int2 pr = pp[i];
        int r = atomicAdd(&cur[pr.x & 255], 1);
        colp[r] = pr.y;
    }
}

// ================= MFMA Q/K/V projection =================
static __device__ __forceinline__ short8 pack8(const float* p) {
    float4 a = *(const float4*)p;
    float4 b = *(const float4*)(p + 4);
    short8 v;
    v[0] = (short)f2bf(a.x); v[1] = (short)f2bf(a.y);
    v[2] = (short)f2bf(a.z); v[3] = (short)f2bf(a.w);
    v[4] = (short)f2bf(b.x); v[5] = (short)f2bf(b.y);
    v[6] = (short)f2bf(b.z); v[7] = (short)f2bf(b.w);
    return v;
}

template<int NT, int A, bool BF>
__device__ __forceinline__ void mat_mfma(
    const short8* xf, const unsigned short* W, const float* b,
    void* o, int node0, int r, int kg)
{
    floatx4 acc[NT];
#pragma unroll
    for (int nt = 0; nt < NT; ++nt) {
        float bb = b[nt * 16 + r];
        acc[nt] = (floatx4){bb, bb, bb, bb};
    }
#pragma unroll
    for (int ks = 0; ks < 4; ++ks) {
#pragma unroll
        for (int nt = 0; nt < NT; ++nt) {
            short8 wf = *(const short8*)((const short*)W + (size_t)(nt * 16 + r) * IN_F + ks * 32 + kg * 8);
            acc[nt] = __builtin_amdgcn_mfma_f32_16x16x32_bf16(xf[ks], wf, acc[nt], 0, 0, 0);
        }
    }
#pragma unroll
    for (int nt = 0; nt < NT; ++nt)
#pragma unroll
        for (int reg = 0; reg < 4; ++reg) {
            size_t idx = (size_t)(node0 + kg * 4 + reg) * A + nt * 16 + r;
            if constexpr (BF) ((unsigned short*)o)[idx] = f2bf(acc[nt][reg]);
            else              ((float*)o)[idx] = acc[nt][reg];
        }
}

template<int A>
__global__ __launch_bounds__(256) void qkv_mfma(
    const float* __restrict__ x,
    const unsigned short* __restrict__ Wqb, const float* __restrict__ bq,
    const unsigned short* __restrict__ Wkb, const float* __restrict__ bk,
    const unsigned short* __restrict__ Wvb, const float* __restrict__ bv,
    float* __restrict__ qo, unsigned short* __restrict__ ko, unsigned short* __restrict__ vo,
    int n)
{
    constexpr int NT = A / 16;
    const int wave = threadIdx.x >> 6;
    const int lane = threadIdx.x & 63;
    const int node0 = blockIdx.x * 64 + wave * 16;
    if (node0 >= n) return;
    const int r  = lane & 15;
    const int kg = lane >> 4;

    short8 xf[4];
    const float* xr = x + (size_t)(node0 + r) * IN_F + kg * 8;
#pragma unroll
    for (int ks = 0; ks < 4; ++ks) xf[ks] = pack8(xr + ks * 32);

    mat_mfma<NT, A, false>(xf, Wqb, bq, qo, node0, r, kg);
    mat_mfma<NT, A, true >(xf, Wkb, bk, ko, node0, r, kg);
    mat_mfma<NT, A, true >(xf, Wvb, bv, vo, node0, r, kg);
}

// ================= fused per-node gather (A=128, dk=32), bf16 k/v =================
// One wave per src node. eslot = lane>>4 (4 edges in flight), il = lane&15.
// Lane covers 8 contiguous elements [il*8, il*8+8) = quarter of head il>>2.
// No online max: scores are O(1), exp(s) is safe; softmax is shift-invariant.
template<bool ACCUM, bool ELU>
__global__ __launch_bounds__(256) void gat_node128(
    const float* __restrict__ q, const uint4* __restrict__ kb4,
    const uint4* __restrict__ vb4,
    const int* __restrict__ rowptr, const int* __restrict__ deg,
    const int* __restrict__ col,
    float* __restrict__ out, float beta, float scale, int n)
{
    int wid  = (blockIdx.x * 256 + threadIdx.x) >> 6;
    int lane = threadIdx.x & 63;
    if (wid >= n) return;
    int start = rowptr[wid], cnt = deg[wid];
    int eslot = lane >> 4;
    int il    = lane & 15;

    const float4* qp = (const float4*)(q + (size_t)wid * 128 + il * 8);
    float4 qa = qp[0], qb = qp[1];
    float l = 0.f;
    float ax[8];
#pragma unroll
    for (int j = 0; j < 8; ++j) ax[j] = 0.f;

    for (int t = eslot; t < cnt; t += 4) {
        int d = col[start + t];
        uint4 kw = kb4[(size_t)d * 16 + il];
        uint4 vw = vb4[(size_t)d * 16 + il];
        float2 k0 = bf2f2(kw.x), k1 = bf2f2(kw.y), k2 = bf2f2(kw.z), k3 = bf2f2(kw.w);
        float p = qa.x * k0.x + qa.y * k0.y + qa.z * k1.x + qa.w * k1.y
                + qb.x * k2.x + qb.y * k2.y + qb.z * k3.x + qb.w * k3.y;
        p += __shfl_xor(p, 1);
        p += __shfl_xor(p, 2);          // head-group (4 lanes) reduce
        float e = __expf(p * scale);
        l += e;
        float2 v0 = bf2f2(vw.x), v1 = bf2f2(vw.y), v2 = bf2f2(vw.z), v3 = bf2f2(vw.w);
        ax[0] += e * v0.x; ax[1] += e * v0.y;
        ax[2] += e * v1.x; ax[3] += e * v1.y;
        ax[4] += e * v2.x; ax[5] += e * v2.y;
        ax[6] += e * v3.x; ax[7] += e * v3.y;
    }
    // merge the 4 eslots
#pragma unroll
    for (int off = 16; off <= 32; off <<= 1) {
        l += __shfl_xor(l, off);
#pragma unroll
        for (int j = 0; j < 8; ++j) ax[j] += __shfl_xor(ax[j], off);
    }
    if (eslot == 0) {
        float inv = (l > 0.f) ? beta / l : 0.f;
        float4* op = (float4*)(out + (size_t)wid * 128 + il * 8);
        float r0[8];
        if constexpr (ACCUM) {
            float4 c0 = op[0], c1 = op[1];
            r0[0] = c0.x + ax[0] * inv; r0[1] = c0.y + ax[1] * inv;
            r0[2] = c0.z + ax[2] * inv; r0[3] = c0.w + ax[3] * inv;
            r0[4] = c1.x + ax[4] * inv; r0[5] = c1.y + ax[5] * inv;
            r0[6] = c1.z + ax[6] * inv; r0[7] = c1.w + ax[7] * inv;
        } else {
#pragma unroll
            for (int j = 0; j < 8; ++j) r0[j] = ax[j] * inv;
        }
        if constexpr (ELU) {
#pragma unroll
            for (int j = 0; j < 8; ++j) r0[j] = r0[j] > 0.f ? r0[j] : expm1f(r0[j]);
        }
        op[0] = make_float4(r0[0], r0[1], r0[2], r0[3]);
        op[1] = make_float4(r0[4], r0[5], r0[6], r0[7]);
    }
}

// ================= fused per-node gather (A=32, dk=8), bf16 k/v =================
// One wave per node. eslot = lane>>2 (16 edges in flight), il = lane&3 = head.
// Lane holds a FULL head (8 elems) -> zero-shuffle dot.
template<bool ACCUM, bool FINAL>
__global__ __launch_bounds__(256) void gat_node32(
    const float* __restrict__ q, const uint4* __restrict__ kb4,
    const uint4* __restrict__ vb4,
    const int* __restrict__ rowptr, const int* __restrict__ deg,
    const int* __restrict__ col,
    const float* __restrict__ prev, float* __restrict__ outp,
    float beta, float scale, int n)
{
    int wid  = (blockIdx.x * 256 + threadIdx.x) >> 6;
    int lane = threadIdx.x & 63;
    if (wid >= n) return;
    int start = rowptr[wid], cnt = deg[wid];
    int eslot = lane >> 2;
    int il    = lane & 3;

    const float4* qp = (const float4*)(q + (size_t)wid * 32 + il * 8);
    float4 qa = qp[0], qb = qp[1];
    float l = 0.f;
    float ax[8];
#pragma unroll
    for (int j = 0; j < 8; ++j) ax[j] = 0.f;

    for (int t = eslot; t < cnt; t += 16) {
        int d = col[start + t];
        uint4 kw = kb4[(size_t)d * 4 + il];
        uint4 vw = vb4[(size_t)d * 4 + il];
        float2 k0 = bf2f2(kw.x), k1 = bf2f2(kw.y), k2 = bf2f2(kw.z), k3 = bf2f2(kw.w);
        float p = qa.x * k0.x + qa.y * k0.y + qa.z * k1.x + qa.w * k1.y
                + qb.x * k2.x + qb.y * k2.y + qb.z * k3.x + qb.w * k3.y;
        float e = __expf(p * scale);
        l += e;
        float2 v0 = bf2f2(vw.x), v1 = bf2f2(vw.y), v2 = bf2f2(vw.z), v3 = bf2f2(vw.w);
        ax[0] += e * v0.x; ax[1] += e * v0.y;
        ax[2] += e * v1.x; ax[3] += e * v1.y;
        ax[4] += e * v2.x; ax[5] += e * v2.y;
        ax[6] += e * v3.x; ax[7] += e * v3.y;
    }
    // merge the 16 eslots
#pragma unroll
    for (int off = 4; off <= 32; off <<= 1) {
        l += __shfl_xor(l, off);
#pragma unroll
        for (int j = 0; j < 8; ++j) ax[j] += __shfl_xor(ax[j], off);
    }
    if (eslot == 0) {
        float inv = (l > 0.f) ? beta / l : 0.f;
        float z[8];
        if constexpr (ACCUM) {
            const float4* pp = (const float4*)(prev + (size_t)wid * 32 + il * 8);
            float4 c0 = pp[0], c1 = pp[1];
            z[0] = c0.x + ax[0] * inv; z[1] = c0.y + ax[1] * inv;
            z[2] = c0.z + ax[2] * inv; z[3] = c0.w + ax[3] * inv;
            z[4] = c1.x + ax[4] * inv; z[5] = c1.y + ax[5] * inv;
            z[6] = c1.z + ax[6] * inv; z[7] = c1.w + ax[7] * inv;
        } else {
#pragma unroll
            for (int j = 0; j < 8; ++j) z[j] = ax[j] * inv;
        }
        if constexpr (FINAL) {
            // log_softmax over 32 classes: 8 in-lane + reduce over 4 lanes
            float mx = z[0];
#pragma unroll
            for (int j = 1; j < 8; ++j) mx = fmaxf(mx, z[j]);
            mx = fmaxf(mx, __shfl_xor(mx, 1));
            mx = fmaxf(mx, __shfl_xor(mx, 2));
            float sm = 0.f;
#pragma unroll
            for (int j = 0; j < 8; ++j) sm += __expf(z[j] - mx);
            sm += __shfl_xor(sm, 1);
            sm += __shfl_xor(sm, 2);
            float lse = mx + logf(sm);
#pragma unroll
            for (int j = 0; j < 8; ++j) z[j] -= lse;
        }
        float4* op = (float4*)(outp + (size_t)wid * 32 + il * 8);
        op[0] = make_float4(z[0], z[1], z[2], z[3]);
        op[1] = make_float4(z[4], z[5], z[6], z[7]);
    }
}

extern "C" void kernel_launch(void* const* d_in, const int* in_sizes, int n_in,
                              void* d_out, int out_size, void* d_ws, size_t ws_size,
                              hipStream_t stream)
{
    const float* x   = (const float*)d_in[0];
    const float* Wq0 = (const float*)d_in[1];
    const float* bq0 = (const float*)d_in[2];
    const float* Wk0 = (const float*)d_in[3];
    const float* bk0 = (const float*)d_in[4];
    const float* Wv0 = (const float*)d_in[5];
    const float* bv0 = (const float*)d_in[6];
    const float* Wq1 = (const float*)d_in[7];
    const float* bq1 = (const float*)d_in[8];
    const float* Wk1 = (const float*)d_in[9];
    const float* bk1 = (const float*)d_in[10];
    const float* Wv1 = (const float*)d_in[11];
    const float* bv1 = (const float*)d_in[12];
    const int* e0 = (const int*)d_in[13];
    const int* e1 = (const int*)d_in[14];
    const int* e2 = (const int*)d_in[15];
    const int* e3 = (const int*)d_in[16];

    char* w = (char*)d_ws;
    float*          q   = (float*)w;          w += (size_t)N_NODES * HID * 4;
    unsigned short* kb  = (unsigned short*)w; w += (size_t)N_NODES * HID * 2;
    unsigned short* vb  = (unsigned short*)w; w += (size_t)N_NODES * HID * 2;
    float*          acc = (float*)w;          w += (size_t)N_NODES * HID * 4;  // h after ELU
    float*          lg  = (float*)w;          w += (size_t)N_NODES * CLS * 4;
    int* deg    = (int*)w; w += (size_t)4 * N_NODES * 4;
    int* rowptr = (int*)w; w += (size_t)4 * N_NODES * 4;
    int* col    = (int*)w; w += (size_t)4 * N_EDGES * 4;
    int* bcnt   = (int*)w; w += (size_t)4 * NBUCK * 4;
    int* bbase  = (int*)w; w += (size_t)4 * (NBUCK + 1) * 4;
    int* bcur   = (int*)w; w += (size_t)4 * NBUCK * 4;
    unsigned short* wq0b = (unsigned short*)w; w += (size_t)2 * HID * IN_F * 2;
    unsigned short* wk0b = (unsigned short*)w; w += (size_t)2 * HID * IN_F * 2;
    unsigned short* wv0b = (unsigned short*)w; w += (size_t)2 * HID * IN_F * 2;
    unsigned short* wq1b = (unsigned short*)w; w += (size_t)2 * CLS * IN_F * 2;
    unsigned short* wk1b = (unsigned short*)w; w += (size_t)2 * CLS * IN_F * 2;
    unsigned short* wv1b = (unsigned short*)w; w += (size_t)2 * CLS * IN_F * 2;

    // pairs buffer (25.6 MB) aliases q — only live during CSR build, before any qkv
    int2* pairs = (int2*)q;

    float* out = (float*)d_out;
    const int NB = (N_NODES + 3) / 4;          // gat: 4 waves / block
    const int QB = (N_NODES / 16 + 3) / 4;     // qkv: 4 waves (16 nodes) / block

    // ---------- weights -> bf16 ----------
    const int W0 = 2 * HID * IN_F, W1 = 2 * CLS * IN_F;
    conv3<<<dim3((W0 + 255) / 256, 3), 256, 0, stream>>>(Wq0, Wk0, Wv0, wq0b, wk0b, wv0b, W0);
    conv3<<<dim3((W1 + 255) / 256, 3), 256, 0, stream>>>(Wq1, Wk1, Wv1, wq1b, wk1b, wv1b, W1);

    // ---------- build 4 CSRs (bucket counting sort) ----------
    hipMemsetAsync(bcnt, 0, (size_t)4 * NBUCK * 4, stream);
    bucket_hist<<<dim3(256, 4), 256, 0, stream>>>(e0, e1, e2, e3, bcnt, N_EDGES);
    bucket_scan<<<4, 256, 0, stream>>>(bcnt, bbase, bcur);
    pass1_scatter<<<dim3((N_EDGES + TILE - 1) / TILE, 4), 256, 0, stream>>>(
        e0, e1, e2, e3, bcur, pairs, N_EDGES);
    pass2_place<<<dim3(NBUCK, 4), 256, 0, stream>>>(
        pairs, bbase, rowptr, deg, col, N_EDGES, N_NODES);

    // ================= layer 0 (A=128, dk=32) =================
    for (int hop = 0; hop < 2; ++hop) {
        qkv_mfma<HID><<<QB, 256, 0, stream>>>(
            x,
            wq0b + (size_t)hop * HID * IN_F, bq0 + (size_t)hop * HID,
            wk0b + (size_t)hop * HID * IN_F, bk0 + (size_t)hop * HID,
            wv0b + (size_t)hop * HID * IN_F, bv0 + (size_t)hop * HID,
            q, kb, vb, N_NODES);
        const int* rp = rowptr + (size_t)hop * N_NODES;
        const int* dg = deg + (size_t)hop * N_NODES;
        const int* cl = col + (size_t)hop * N_EDGES;
        if (hop == 0)
            gat_node128<false, false><<<NB, 256, 0, stream>>>(
                q, (const uint4*)kb, (const uint4*)vb, rp, dg, cl,
                acc, 1.0f, 1.f / sqrtf(32.f), N_NODES);
        else
            gat_node128<true, true><<<NB, 256, 0, stream>>>(
                q, (const uint4*)kb, (const uint4*)vb, rp, dg, cl,
                acc, 0.5f, 1.f / sqrtf(32.f), N_NODES);
    }

    // ================= layer 1 (A=32, dk=8) =================
    for (int hop = 0; hop < 2; ++hop) {
        qkv_mfma<CLS><<<QB, 256, 0, stream>>>(
            acc,
            wq1b + (size_t)hop * CLS * IN_F, bq1 + (size_t)hop * CLS,
            wk1b + (size_t)hop * CLS * IN_F, bk1 + (size_t)hop * CLS,
            wv1b + (size_t)hop * CLS * IN_F, bv1 + (size_t)hop * CLS,
            q, kb, vb, N_NODES);
        const int* rp = rowptr + (size_t)(2 + hop) * N_NODES;
        const int* dg = deg + (size_t)(2 + hop) * N_NODES;
        const int* cl = col + (size_t)(2 + hop) * N_EDGES;
        if (hop == 0)
            gat_node32<false, false><<<NB, 256, 0, stream>>>(
                q, (const uint4*)kb, (const uint4*)vb, rp, dg, cl,
                nullptr, lg, 1.0f, 1.f / sqrtf(8.f), N_NODES);
        else
            gat_node32<true, true><<<NB, 256, 0, stream>>>(
                q, (const uint4*)kb, (const uint4*)vb, rp, dg, cl,
                lg, out, 0.5f, 1.f / sqrtf(8.f), N_NODES);
    }
}